// Round 11
// baseline (1302.834 us; speedup 1.0000x reference)
//
#include <hip/hip_runtime.h>
#include <hip/hip_bf16.h>
#include <cstdint>
#include <cstddef>

#define N_MOLS 256
#define NN     8192
#define SDIM_  256
#define NAF_   16
#define LAYERS_ 5

typedef __attribute__((ext_vector_type(8)))  short bf16x8;
typedef __attribute__((ext_vector_type(16))) float f32x16;
typedef __attribute__((ext_vector_type(4)))  float f32x4;

// fast silu: v_rcp instead of IEEE divide.
__device__ __forceinline__ float silu_f(float x) {
    return x * __builtin_amdgcn_rcpf(1.f + __expf(-x));
}
__device__ __forceinline__ short bfc(float f) {
    __hip_bfloat16 h = __float2bfloat16(f);
    return __builtin_bit_cast(short, h);
}
__device__ __forceinline__ float bf2f(short h) {
    union { uint32_t u; float f; } v; v.u = ((uint32_t)(unsigned short)h) << 16; return v.f;
}
#define ONEBF ((short)0x3F80)

// ---------------------------------------------------------------------------
// weight image offsets (in shorts, within wb)
// ---------------------------------------------------------------------------
#define OFF_T1    0         // 5 * 512*256   : W1ab^T  [l][j2][k]
#define OFF_W2ST  655360    // 5 * 256*256   : W2s^T   [l][n][k]
#define OFF_WH1T  983040    // 256*256       : Wh1^T   [n][k]
#define OFF_WE1T  1048576   // 128*256       : We1^T   [n][k]
#define OFF_W1CG  1081344   // 5 * 256*32    : W1c slot groups [l][j][w]
#define OFF_W1DA  1122304   // 5 * 2*256    : W1 d/a rows
#define OFF_W2P   1124864   // 5 * 256       : W2 col 320
#define OFF_W2EI  1126144   // 5 * 8192      : sW2e fragment image
#define OFF_WE1CG 1167104   // 128*32        : We1c slot groups
#define OFF_WD    1171200   // 128           : We1 row 288
#define OFF_WE2I  1171328   // 8*64*8        : We2 fragment image
#define OFF_WH2T  1175424   // 16*256        : Wh2^T [n=16][k=256]
#define W_TOTAL   1179520

// ---------------------------------------------------------------------------
// merged init: blocks [0,1024) weight images; [1024,1280) node init;
// [1280,1536) edge init. All three independent.
// ---------------------------------------------------------------------------
__global__ __launch_bounds__(256) void init_all(
    const float* __restrict__ x, const float* __restrict__ z,
    const float* __restrict__ rot, const float* __restrict__ Wam,
    const float* __restrict__ bam, const float* __restrict__ ea,
    const float* __restrict__ Wbm, const float* __restrict__ bbm,
    const float* __restrict__ gW1, const float* __restrict__ gW2,
    const float* __restrict__ Wh1, const float* __restrict__ We1,
    const float* __restrict__ We2, const float* __restrict__ Wh2,
    float* __restrict__ s, short* __restrict__ sbf, float* __restrict__ pos,
    short* __restrict__ ebuf, short* __restrict__ wb)
{
    __shared__ __align__(16) char smem[20608];
    const int b = blockIdx.x, t = threadIdx.x;
    if (b < 1024) {
        for (int o = b * 256 + t; o < W_TOTAL; o += 1024 * 256) {
            float v;
            if (o < OFF_W2ST) {                       // T1 [l][j2<512][k<256]
                const int l = o >> 17, r = o & 131071;
                const int j2 = r >> 8, k = r & 255;
                v = gW1[(size_t)l * 139776 + (size_t)((j2 >> 8) * 256 + k) * 256 + (j2 & 255)];
            } else if (o < OFF_WH1T) {                // W2sT [l][n][k]
                const int q = o - OFF_W2ST;
                const int l = q >> 16, r = q & 65535;
                const int n = r >> 8, k = r & 255;
                v = gW2[(size_t)l * 90368 + (size_t)k * 353 + n];
            } else if (o < OFF_WE1T) {                // Wh1T [n][k]
                const int q = o - OFF_WH1T;
                v = Wh1[(size_t)(q & 255) * 256 + (q >> 8)];
            } else if (o < OFF_W1CG) {                // We1T [n][k]
                const int q = o - OFF_WE1T;
                v = We1[(size_t)(q & 255) * 128 + (q >> 8)];
            } else if (o < OFF_W1DA) {                // W1cG [l][j][w]
                const int q = o - OFF_W1CG;
                const int l = q >> 13, r = q & 8191;
                const int j = r >> 5, w = r & 31;
                v = gW1[(size_t)l * 139776 + (size_t)(512 + w) * 256 + j];
            } else if (o < OFF_W2P) {                 // W1da [l][d][j]
                const int q = o - OFF_W1DA;
                const int l = q >> 9, r = q & 511;
                v = gW1[(size_t)l * 139776 + (size_t)(544 + (r >> 8)) * 256 + (r & 255)];
            } else if (o < OFF_W2EI) {                // W2p [l][j]
                const int q = o - OFF_W2P;
                v = gW2[(size_t)(q >> 8) * 90368 + (size_t)(q & 255) * 353 + 320];
            } else if (o < OFF_WE1CG) {               // W2e fragment image [l][idx]
                const int q = o - OFF_W2EI;
                const int l = q >> 13, r = q & 8191;
                const int kk = r >> 9, lanei = (r >> 3) & 63, jj = r & 7;
                const int j = kk * 16 + (lanei >> 5) * 8 + jj;
                v = gW2[(size_t)l * 90368 + (size_t)j * 353 + 321 + (lanei & 31)];
            } else if (o < OFF_WD) {                  // We1cG [j][w]
                const int q = o - OFF_WE1CG;
                v = We1[(size_t)(256 + (q & 31)) * 128 + (q >> 5)];
            } else if (o < OFF_WE2I) {                // Wd [j]
                v = We1[288 * 128 + (o - OFF_WD)];
            } else if (o < OFF_WH2T) {                // We2 fragment image
                const int q = o - OFF_WE2I;
                const int kk = q >> 9, lanei = (q >> 3) & 63, jj = q & 7;
                const int c = lanei & 31;
                v = (c < 5) ? We2[(size_t)(kk * 16 + (lanei >> 5) * 8 + jj) * 5 + c] : 0.f;
            } else {                                  // Wh2T [n=16][k=256]
                const int q = o - OFF_WH2T;
                v = Wh2[(size_t)(q & 255) * 16 + (q >> 8)];
            }
            wb[o] = bfc(v);
        }
    } else if (b < 1280) {
        // ---- node init
        const int mol = b - 1024;
        float (*xz)[80]  = (float(*)[80])smem;
        float (*praw)[3] = (float(*)[3])(smem + 32 * 80 * 4);
        for (int idx = t; idx < 32 * 80; idx += 256) {
            const int i = idx / 80, k = idx % 80;
            xz[i][k] = (k < 16) ? x[(size_t)(mol * 32 + i) * 16 + k]
                                : z[(size_t)(mol * 32 + i) * 64 + (k - 16)];
        }
        __syncthreads();
        float acc[32];
        #pragma unroll
        for (int i = 0; i < 32; ++i) acc[i] = 0.f;
        for (int k0 = 0; k0 < 80; k0 += 4) {
            const float w0 = Wam[(k0 + 0) * 259 + t];
            const float w1 = Wam[(k0 + 1) * 259 + t];
            const float w2 = Wam[(k0 + 2) * 259 + t];
            const float w3 = Wam[(k0 + 3) * 259 + t];
            #pragma unroll
            for (int i = 0; i < 32; ++i) {
                const float4 xv = *(const float4*)&xz[i][k0];
                acc[i] += xv.x * w0 + xv.y * w1 + xv.z * w2 + xv.w * w3;
            }
        }
        const float bv = bam[t];
        #pragma unroll
        for (int i = 0; i < 32; ++i) {
            const float v = acc[i] + bv;
            s[(size_t)(mol * 32 + i) * 256 + t] = v;
            sbf[(size_t)(mol * 32 + i) * 256 + t] = bfc(v);
        }
        if (t < 96) {
            const int i = t / 3, c = t % 3;
            float a2 = bam[256 + c];
            for (int k = 0; k < 80; ++k) a2 += xz[i][k] * Wam[k * 259 + 256 + c];
            praw[i][c] = a2;
        }
        __syncthreads();
        if (t < 96) {
            const int i = t / 3, c = t % 3;
            float p = 0.f;
            for (int jj = 0; jj < 3; ++jj) p += rot[mol * 9 + c * 3 + jj] * praw[i][jj];
            pos[(size_t)(mol * 32 + i) * 3 + c] = p;
        }
    } else {
        // ---- edge init
        const int mol = b - 1280;
        float* sEa      = (float*)smem;
        float (*sW)[32] = (float(*)[32])(smem + 4960 * 4);
        float* sB       = (float*)(smem + (4960 + 160) * 4);
        const float* base = ea + (size_t)mol * 4960;
        for (int i = t; i < 4960; i += 256) sEa[i] = base[i];
        if (t < 160) sW[t / 32][t & 31] = Wbm[t];
        if (t < 32)  sB[t] = bbm[t];
        __syncthreads();
        for (int i = t; i < 31744; i += 256) {
            const int c = i & 31;
            const int rrn = i >> 5;
            const int n = rrn / 31, rr = rrn - n * 31;
            const int s_ = rr + (rr >= n ? 1 : 0);
            const int gl = s_ * 31 + (n - (n > s_ ? 1 : 0));
            float acc = sB[c];
            #pragma unroll
            for (int k = 0; k < 5; ++k) acc += sEa[gl * 5 + k] * sW[k][c];
            ebuf[(size_t)mol * 31744 + i] = bfc(acc);
        }
    }
}

// ---------------------------------------------------------------------------
// merged 5-layer per-molecule kernel. Grid 256, 1024 thr (16 waves).
// All cross-layer deps are molecule-local -> kernel relaunch replaced by
// __syncthreads(). sSbfP (bf16 s-mirror) and sPosS persist in LDS.
// 16 waves = two virtual 8-wave blocks (vb = wave>>3) running r9's phases.
// r11: amdgpu_waves_per_eu(4,4) pins the allocator to 4 waves/EU -> VGPR
// budget 128 (the count r9's identical bodies compiled to). Plain
// launch_bounds(1024) alone made the heuristic pick VGPR=64 -> 2.7 GB of
// scratch spill traffic per dispatch (r10: 1140us). LDS (130KB) limits to
// 1 block/CU anyway, so 4 waves/EU loses nothing.
// ---------------------------------------------------------------------------
__global__ __attribute__((amdgpu_waves_per_eu(4, 4))) __launch_bounds__(1024)
void mol_layers(
    short* __restrict__ sbf_g, float* __restrict__ pos_g,
    short* __restrict__ ebuf, const short* __restrict__ wb,
    const float* __restrict__ gb1, const float* __restrict__ gb2,
    float* __restrict__ s)
{
    const int mol = blockIdx.x;
    const int t = threadIdx.x;
    const int w = t >> 6, lane = t & 63;
    const int l = lane & 31, half = lane >> 5;
    const int vw = w & 7, vb = w >> 3;
    const int nbase = vb * 16;
    const int node0 = mol * 32;

    __shared__ __align__(16) short sBg[256][72];      // 36 KB (shared, 1 copy)
    __shared__ __align__(16) short sM[16][32][40];    // 40 KB per-wave hdn scratch
    __shared__ __align__(16) short sHrows[32][264];   // 16.9 KB
    __shared__ __align__(16) short sSB[32][264];      // 16.9 KB
    __shared__ __align__(16) short sSbfP[32][264];    // 16.9 KB persistent bf16 s
    __shared__ float sPosS[32][4];                    // persistent pos
    __shared__ __align__(16) short sW1da[2][256];
    __shared__ __align__(16) short sW2p[256];
    __shared__ float sP[16][32];
    __shared__ float sPd[32][4];

    // ---- one-time staging: sbf + pos into persistent LDS
    {
        const int row = t >> 5, ch = (t & 31) * 8;
        *(bf16x8*)&sSbfP[row][ch] =
            *(const bf16x8*)(sbf_g + (size_t)(node0 + row) * 256 + ch);
    }
    if (t < 96) sPosS[t / 3][t % 3] = pos_g[node0 * 3 + t];

    int bslot[4];
    #pragma unroll
    for (int ks = 0; ks < 4; ++ks)
        bslot[ks] = ((ks * 2 + half) + 3 * ((l >> 3) & 3)) & 7;

    for (int ly = 0; ly < LAYERS_; ++ly) {
        const short* T1     = wb + OFF_T1   + (size_t)ly * 131072;
        const short* W1cG   = wb + OFF_W1CG + ly * 8192;
        const short* W1daP  = wb + OFF_W1DA + ly * 512;
        const short* W2pP   = wb + OFF_W2P  + ly * 256;
        const short* W2eimg = wb + OFF_W2EI + ly * 8192;
        const short* W2sT   = wb + OFF_W2ST + (size_t)ly * 65536;
        const float* b1     = gb1 + ly * 256;
        const float* b2     = gb2 + ly * 353;

        __syncthreads();   // prev layer done (sBg free, sSbfP/sPosS updated)

        // ---- phase 0a: W1c -> sBg k0..31 (1024 thr: 1 chunk each)
        {
            const int j = t & 255, ks = t >> 8;    // ks 0..3
            const bf16x8 v = *(const bf16x8*)&W1cG[j * 32 + ks * 8];
            const int slot = (ks + 3 * ((j >> 3) & 3)) & 7;
            *(bf16x8*)&sBg[j][slot * 8] = v;
        }
        if (t < 64) {
            short* d = &sW1da[0][0];
            *(bf16x8*)&d[t * 8] = *(const bf16x8*)&W1daP[t * 8];
        }
        if (t < 32) *(bf16x8*)&sW2p[t * 8] = *(const bf16x8*)&W2pP[t * 8];

        // ---- phase 0b: split dual GEMM. waves 0-7: SA -> sBg k32..63;
        // waves 8-15: SB -> sSB. (disjoint LDS vs 0a; no sync needed between)
        {
            const int j = vw * 32 + l;
            const short* Bsrc = T1 + (size_t)(vb * 256 + j) * 256;
            f32x16 acc = {};
            #pragma unroll
            for (int k0 = 0; k0 < 256; k0 += 16) {
                const bf16x8 afr = *(const bf16x8*)&sSbfP[l][k0 + half * 8];
                const bf16x8 bfr = *(const bf16x8*)(Bsrc + k0 + half * 8);
                acc = __builtin_amdgcn_mfma_f32_32x32x16_bf16(afr, bfr, acc, 0,0,0);
            }
            const int c3 = (j >> 3) & 3;
            if (vb == 0) {
                #pragma unroll
                for (int r = 0; r < 16; ++r) {
                    const int node = (r & 3) + 8 * (r >> 2) + 4 * half;
                    const int k = 32 + node;
                    const int slot = ((k >> 3) + 3 * c3) & 7;
                    sBg[j][slot * 8 + (k & 7)] = bfc(acc[r]);
                }
            } else {
                #pragma unroll
                for (int r = 0; r < 16; ++r) {
                    const int node = (r & 3) + 8 * (r >> 2) + 4 * half;
                    sSB[node][j] = bfc(acc[r]);
                }
            }
        }
        __syncthreads();

        // ---- per-layer register tables
        float b1v[8];
        short w1dv[8], w1av[8];
        #pragma unroll
        for (int cb = 0; cb < 8; ++cb) {
            b1v[cb]  = b1[cb * 32 + l];
            w1dv[cb] = sW1da[0][cb * 32 + l];
            w1av[cb] = sW1da[1][cb * 32 + l];
        }
        const float b2e = b2[321 + l];
        const float b2p = b2[320];

        // prefetch ebuf fragments for BOTH ni iterations
        bf16x8 efr0[2], efr1[2];
        #pragma unroll
        for (int ni = 0; ni < 2; ++ni) {
            const int n = nbase + vw + ni * 8;
            const short* ebase = ebuf + ((size_t)((mol * 32 + n) * 31 + l)) * 32;
            efr0[ni] = *(const bf16x8*)(ebase + half * 8);
            efr1[ni] = *(const bf16x8*)(ebase + 16 + half * 8);
        }

        // ---- phase 1: edge messages
        #pragma unroll
        for (int ni = 0; ni < 2; ++ni) {
            const int n = nbase + vw + ni * 8;
            const int rrc = (l < 31) ? l : 30;
            const int src = rrc + (rrc >= n ? 1 : 0);
            const float ax = sPosS[n][0],  ay = sPosS[n][1],  az = sPosS[n][2];
            const float bx = sPosS[src][0], by = sPosS[src][1], bz = sPosS[src][2];
            const float rx = ax - bx, ry = ay - by, rz = az - bz;
            const float av = ax * bx + ay * by + az * bz;
            const float dd = sqrtf(fmaxf(rx * rx + ry * ry + rz * rz, 1e-6f));
            const float inv = __builtin_amdgcn_rcpf(1.f + dd);
            const float rnx = rx * inv, rny = ry * inv, rnz = rz * inv;

            const bf16x8 fr0 = efr0[ni];
            const bf16x8 fr1 = efr1[ni];
            bf16x8 fr2 = {}, fr3, fr4;
            if (half == 0) { fr2[0] = bfc(dd); fr2[1] = bfc(av); }
            #pragma unroll
            for (int jj = 0; jj < 8; ++jj) {
                fr3[jj] = (half * 8 + jj == src)      ? ONEBF : (short)0;
                fr4[jj] = (16 + half * 8 + jj == src) ? ONEBF : (short)0;
            }

            const short* W2ei = W2eimg;
            asm volatile("" : "+s"(W2ei));

            f32x16 accC = {}, accP = {};
            float Hacc[8];

            const int g = l >> 3, jlow = l & 7;
            #pragma unroll
            for (int cb = 0; cb < 8; ++cb) {
                const bf16x8 w2e0 = *(const bf16x8*)&W2ei[(size_t)((cb * 2 + 0) * 64 + lane) * 8];
                const bf16x8 w2e1 = *(const bf16x8*)&W2ei[(size_t)((cb * 2 + 1) * 64 + lane) * 8];
                const float sbv = bf2f(sSB[n][cb * 32 + l]) + b1v[cb];
                f32x16 acc;
                #pragma unroll
                for (int r = 0; r < 16; ++r) acc[r] = sbv;
                {
                    const short* brow = &sBg[cb * 32 + l][0];
                    __builtin_amdgcn_s_setprio(1);
                    acc = __builtin_amdgcn_mfma_f32_32x32x16_bf16(fr0, *(const bf16x8*)(brow + bslot[0]*8), acc, 0,0,0);
                    acc = __builtin_amdgcn_mfma_f32_32x32x16_bf16(fr1, *(const bf16x8*)(brow + bslot[1]*8), acc, 0,0,0);
                    acc = __builtin_amdgcn_mfma_f32_32x32x16_bf16(fr3, *(const bf16x8*)(brow + bslot[2]*8), acc, 0,0,0);
                    acc = __builtin_amdgcn_mfma_f32_32x32x16_bf16(fr4, *(const bf16x8*)(brow + bslot[3]*8), acc, 0,0,0);
                    bf16x8 frB2 = {};
                    if (half == 0) { frB2[0] = w1dv[cb]; frB2[1] = w1av[cb]; }
                    acc = __builtin_amdgcn_mfma_f32_32x32x16_bf16(fr2, frB2, acc, 0,0,0);
                    __builtin_amdgcn_s_setprio(0);
                }
                float hs = 0.f;
                #pragma unroll
                for (int r = 0; r < 16; ++r) {
                    const int e = (r & 3) + 8 * (r >> 2) + 4 * half;
                    float h = silu_f(acc[r]);
                    if (half == 1 && r == 15) h = 0.f;   // pad row 31
                    hs += h;
                    sM[w][e][((g + (e >> 3)) & 3) * 8 + jlow] = bfc(h);
                }
                Hacc[cb] = hs;
                #pragma unroll
                for (int q = 0; q < 2; ++q) {
                    const bf16x8 afr  = *(const bf16x8*)&sM[w][l][((q * 2 + half + (l >> 3)) & 3) * 8];
                    const bf16x8 wpfr = *(const bf16x8*)&sW2p[cb * 32 + q * 16 + half * 8];
                    accC = __builtin_amdgcn_mfma_f32_32x32x16_bf16(afr, q ? w2e1 : w2e0, accC, 0,0,0);
                    accP = __builtin_amdgcn_mfma_f32_32x32x16_bf16(afr, wpfr, accP, 0,0,0);
                }
            }
            // H row into LDS tile (bf16)
            #pragma unroll
            for (int cb = 0; cb < 8; ++cb) {
                const float v = Hacc[cb] + __shfl_xor(Hacc[cb], 32, 64);
                if (lane < 32) sHrows[n][cb * 32 + lane] = bfc(v);
            }
            // p scatter
            if (l == 0) {
                #pragma unroll
                for (int q4 = 0; q4 < 4; ++q4) {
                    float4 pv = { accP[q4 * 4 + 0], accP[q4 * 4 + 1],
                                  accP[q4 * 4 + 2], accP[q4 * 4 + 3] };
                    *(float4*)&sP[w][q4 * 8 + 4 * half] = pv;
                }
            }
            const float pown = sP[w][l];
            const float pfull = (half == 0 && l < 31) ? (pown + b2p) : 0.f;
            float pd0 = rnx * pfull, pd1 = rny * pfull, pd2 = rnz * pfull;
            #pragma unroll
            for (int m = 1; m <= 32; m <<= 1) {
                pd0 += __shfl_xor(pd0, m, 64);
                pd1 += __shfl_xor(pd1, m, 64);
                pd2 += __shfl_xor(pd2, m, 64);
            }
            if (lane == 0) {
                sPd[n][0] = pd0;
                sPd[n][1] = pd1;
                sPd[n][2] = pd2;
            }
            // e update (bf16 RMW)
            #pragma unroll
            for (int r = 0; r < 16; ++r) {
                const int e = (r & 3) + 8 * (r >> 2) + 4 * half;
                if (e < 31) {
                    short* ep = ebuf + ((size_t)((mol * 32 + n) * 31 + e)) * 32 + l;
                    *ep = bfc(bf2f(*ep) + accC[r] + b2e);
                }
            }
        }

        __syncthreads();  // H-tile + sPd complete; sPosS reads done

        // ---- phase 2: s-update via 16x16x32 MFMA (vb selects row-half)
        {
            const int jb0 = vw * 32;
            const int arow = lane & 15, kg = lane >> 4;
            const int lrow = nbase + arow;
            f32x4 accS0 = {}, accS1 = {};
            #pragma unroll
            for (int k0 = 0; k0 < 256; k0 += 32) {
                const bf16x8 afr = *(const bf16x8*)&sHrows[lrow][k0 + kg * 8];
                const bf16x8 bf0 = *(const bf16x8*)&W2sT[(size_t)(jb0 + arow) * 256 + k0 + kg * 8];
                const bf16x8 bf1 = *(const bf16x8*)&W2sT[(size_t)(jb0 + 16 + arow) * 256 + k0 + kg * 8];
                accS0 = __builtin_amdgcn_mfma_f32_16x16x32_bf16(afr, bf0, accS0, 0,0,0);
                accS1 = __builtin_amdgcn_mfma_f32_16x16x32_bf16(afr, bf1, accS1, 0,0,0);
            }
            const int col = lane & 15;
            const int orow = (lane >> 4) * 4;
            const float bv0 = b2[jb0 + col];
            const float bv1 = b2[jb0 + 16 + col];
            #pragma unroll
            for (int r = 0; r < 4; ++r) {
                const int nl = nbase + orow + r;
                const int node = node0 + nl;
                {
                    float* sp = s + (size_t)node * 256 + jb0 + col;
                    const float nv = *sp + accS0[r] * (1.f / 31.f) + bv0;
                    *sp = nv;
                    const short bv = bfc(nv);
                    sSbfP[nl][jb0 + col] = bv;
                    if (ly == LAYERS_ - 1) sbf_g[(size_t)node * 256 + jb0 + col] = bv;
                }
                {
                    float* sp = s + (size_t)node * 256 + jb0 + 16 + col;
                    const float nv = *sp + accS1[r] * (1.f / 31.f) + bv1;
                    *sp = nv;
                    const short bv = bfc(nv);
                    sSbfP[nl][jb0 + 16 + col] = bv;
                    if (ly == LAYERS_ - 1) sbf_g[(size_t)node * 256 + jb0 + 16 + col] = bv;
                }
            }
        }
        // pos update (in persistent LDS; global only after last layer)
        if (t < 96) {
            const int nl = t / 3, c = t % 3;
            const float np = sPosS[nl][c] + sPd[nl][c] * (1.f / 31.f);
            sPosS[nl][c] = np;
            if (ly == LAYERS_ - 1) pos_g[(size_t)(node0 + nl) * 3 + c] = np;
        }
    }
}

// ---------------------------------------------------------------------------
// MFMA bond kernel: fused U-GEMM prologue, atoms epilogue, pos output copy.
// Grid 512, 512 thr.
// ---------------------------------------------------------------------------
__global__ __launch_bounds__(512) void bond_mfma(
    const short* __restrict__ sbfA, const short* __restrict__ We1T,
    const float* __restrict__ pos, short* __restrict__ ebuf,
    const short* __restrict__ We1cG, const short* __restrict__ WdP,
    const short* __restrict__ We2img, const short* __restrict__ Wh1T,
    const short* __restrict__ Wh2I,
    const float* __restrict__ be1, const float* __restrict__ be2,
    const float* __restrict__ bh1, const float* __restrict__ bh2,
    float* __restrict__ outA, float* __restrict__ outB,
    float* __restrict__ outPos)
{
    const int blk = blockIdx.x;
    const int mol = blk >> 1;
    const int nbase = (blk & 1) * 16;
    const int t = threadIdx.x;
    const int wave = t >> 6, lane = t & 63;
    const int l = lane & 31, half = lane >> 5;
    const int node0 = mol * 32;

    __shared__ __align__(16) short sBg2[128][72];
    __shared__ __align__(16) short sHdnB[8][32][40];
    __shared__ __align__(16) short sU[32][136];
    __shared__ float sPosS[32][4];
    __shared__ __align__(16) short sWd[128];
    short* sSbf = &sHdnB[0][0][0];   // [32][264] view, phase0 only

    {
        const int j = t & 127, g = t >> 7;
        const bf16x8 v = *(const bf16x8*)&We1cG[j * 32 + g * 8];
        const int slot = (g + 3 * ((j >> 3) & 3)) & 7;
        *(bf16x8*)&sBg2[j][slot * 8] = v;
    }
    {
        const int row = t >> 4, ch = (t & 15) * 16;
        const short* src = sbfA + (size_t)(node0 + row) * 256 + ch;
        *(bf16x8*)&sSbf[row * 264 + ch]     = *(const bf16x8*)(src);
        *(bf16x8*)&sSbf[row * 264 + ch + 8] = *(const bf16x8*)(src + 8);
    }
    if (t < 16) *(bf16x8*)&sWd[t * 8] = *(const bf16x8*)&WdP[t * 8];
    if (t < 96) sPosS[t / 3][t % 3] = pos[node0 * 3 + t];
    __syncthreads();

    if (wave < 4) {
        const int j = wave * 32 + l;
        f32x16 accU = {};
        #pragma unroll
        for (int k0 = 0; k0 < 256; k0 += 16) {
            const bf16x8 afr = *(const bf16x8*)&sSbf[l * 264 + k0 + half * 8];
            const bf16x8 bU  = *(const bf16x8*)(We1T + (size_t)j * 256 + k0 + half * 8);
            accU = __builtin_amdgcn_mfma_f32_32x32x16_bf16(afr, bU, accU, 0,0,0);
        }
        const int c3 = (j >> 3) & 3;
        #pragma unroll
        for (int r = 0; r < 16; ++r) {
            const int node = (r & 3) + 8 * (r >> 2) + 4 * half;
            const short uv = bfc(accU[r]);
            const int k = 32 + node;
            const int slot = ((k >> 3) + 3 * c3) & 7;
            sBg2[j][slot * 8 + (k & 7)] = uv;
            sU[node][j] = uv;
        }
    }

    float be1v[4];
    #pragma unroll
    for (int cb = 0; cb < 4; ++cb) be1v[cb] = be1[cb * 32 + l];
    const float be2v = (l < 5) ? be2[l] : 0.f;
    int bslot[4];
    #pragma unroll
    for (int ks = 0; ks < 4; ++ks)
        bslot[ks] = ((ks * 2 + half) + 3 * ((l >> 3) & 3)) & 7;
    __syncthreads();

    bf16x8 efr0[2], efr1[2];
    #pragma unroll
    for (int ni = 0; ni < 2; ++ni) {
        const int n = nbase + wave + ni * 8;
        const short* ebase = ebuf + ((size_t)((mol * 32 + n) * 31 + l)) * 32;
        efr0[ni] = *(const bf16x8*)(ebase + half * 8);
        efr1[ni] = *(const bf16x8*)(ebase + 16 + half * 8);
    }

    #pragma unroll
    for (int ni = 0; ni < 2; ++ni) {
        const int n = nbase + wave + ni * 8;
        const int rrc = (l < 31) ? l : 30;
        const int src = rrc + (rrc >= n ? 1 : 0);
        const float rx = sPosS[n][0] - sPosS[src][0];
        const float ry = sPosS[n][1] - sPosS[src][1];
        const float rz = sPosS[n][2] - sPosS[src][2];
        const float dd = sqrtf(fmaxf(rx * rx + ry * ry + rz * rz, 1e-6f));

        const bf16x8 fr0 = efr0[ni];
        const bf16x8 fr1 = efr1[ni];
        bf16x8 fr2 = {}, fr3, fr4;
        if (half == 0) fr2[0] = bfc(dd);
        #pragma unroll
        for (int jj = 0; jj < 8; ++jj) {
            fr3[jj] = (half * 8 + jj == src)      ? ONEBF : (short)0;
            fr4[jj] = (16 + half * 8 + jj == src) ? ONEBF : (short)0;
        }

        const short* We2i = We2img;
        asm volatile("" : "+s"(We2i));

        f32x16 accC = {};
        const int g = l >> 3, jlow = l & 7;
        #pragma unroll
        for (int cb = 0; cb < 4; ++cb) {
            const bf16x8 w2f0 = *(const bf16x8*)&We2i[(size_t)((cb * 2 + 0) * 64 + lane) * 8];
            const bf16x8 w2f1 = *(const bf16x8*)&We2i[(size_t)((cb * 2 + 1) * 64 + lane) * 8];
            const float uin = bf2f(sU[n][cb * 32 + l]) + be1v[cb];
            f32x16 acc;
            #pragma unroll
            for (int r = 0; r < 16; ++r) acc[r] = uin;
            {
                const short* brow = &sBg2[cb * 32 + l][0];
                acc = __builtin_amdgcn_mfma_f32_32x32x16_bf16(fr0, *(const bf16x8*)(brow + bslot[0]*8), acc, 0,0,0);
                acc = __builtin_amdgcn_mfma_f32_32x32x16_bf16(fr1, *(const bf16x8*)(brow + bslot[1]*8), acc, 0,0,0);
                acc = __builtin_amdgcn_mfma_f32_32x32x16_bf16(fr3, *(const bf16x8*)(brow + bslot[2]*8), acc, 0,0,0);
                acc = __builtin_amdgcn_mfma_f32_32x32x16_bf16(fr4, *(const bf16x8*)(brow + bslot[3]*8), acc, 0,0,0);
                bf16x8 frWd = {};
                if (half == 0) frWd[0] = sWd[cb * 32 + l];
                acc = __builtin_amdgcn_mfma_f32_32x32x16_bf16(fr2, frWd, acc, 0,0,0);
            }
            #pragma unroll
            for (int r = 0; r < 16; ++r) {
                const int e = (r & 3) + 8 * (r >> 2) + 4 * half;
                sHdnB[wave][e][((g + (e >> 3)) & 3) * 8 + jlow] = bfc(silu_f(acc[r]));
            }
            #pragma unroll
            for (int q = 0; q < 2; ++q) {
                const bf16x8 afr = *(const bf16x8*)&sHdnB[wave][l][((q * 2 + half + (l >> 3)) & 3) * 8];
                accC = __builtin_amdgcn_mfma_f32_32x32x16_bf16(afr, q ? w2f1 : w2f0, accC, 0,0,0);
            }
        }
        if (l < 5) {
            #pragma unroll
            for (int r = 0; r < 16; ++r) {
                const int e = (r & 3) + 8 * (r >> 2) + 4 * half;
                if (e < 31) {
                    const int s_ = e + (e >= n ? 1 : 0);
                    const int ge = (mol * 32 + s_) * 31 + (n - (n > s_ ? 1 : 0));
                    outB[(size_t)ge * 5 + l] = accC[r] + be2v;
                }
            }
        }
    }
    if (t < 48) {
        const int nl = t / 3, c = t % 3;
        const int node = node0 + nbase + nl;
        outPos[(size_t)node * 3 + c] = pos[(size_t)node * 3 + c];
    }

    // ---- phase 3: atoms
    __syncthreads();
    {
        short* sA3 = &sU[0][0];
        const int row = t >> 5, ch = (t & 31) * 8;
        *(bf16x8*)&sA3[row * 264 + ch] =
            *(const bf16x8*)(sbfA + (size_t)(node0 + nbase + row) * 256 + ch);
    }
    __syncthreads();
    {
        short* sA3 = &sU[0][0];
        short* sT  = &sBg2[0][0];
        const int jb0 = wave * 32;
        const int arow = lane & 15, kg = lane >> 4;
        f32x4 a0 = {}, a1 = {};
        #pragma unroll
        for (int k0 = 0; k0 < 256; k0 += 32) {
            const bf16x8 afr = *(const bf16x8*)&sA3[arow * 264 + k0 + kg * 8];
            const bf16x8 bw0 = *(const bf16x8*)(Wh1T + (size_t)(jb0 + arow) * 256 + k0 + kg * 8);
            const bf16x8 bw1 = *(const bf16x8*)(Wh1T + (size_t)(jb0 + 16 + arow) * 256 + k0 + kg * 8);
            a0 = __builtin_amdgcn_mfma_f32_16x16x32_bf16(afr, bw0, a0, 0,0,0);
            a1 = __builtin_amdgcn_mfma_f32_16x16x32_bf16(afr, bw1, a1, 0,0,0);
        }
        const int col = lane & 15, orow = (lane >> 4) * 4;
        const float bva = bh1[jb0 + col], bvb = bh1[jb0 + 16 + col];
        #pragma unroll
        for (int r = 0; r < 4; ++r) {
            sT[(orow + r) * 264 + jb0 + col]      = bfc(silu_f(a0[r] + bva));
            sT[(orow + r) * 264 + jb0 + 16 + col] = bfc(silu_f(a1[r] + bvb));
        }
    }
    __syncthreads();
    if (wave == 0) {
        short* sT = &sBg2[0][0];
        const int arow = lane & 15, kg = lane >> 4;
        f32x4 a2 = {};
        #pragma unroll
        for (int k0 = 0; k0 < 256; k0 += 32) {
            const bf16x8 afr = *(const bf16x8*)&sT[arow * 264 + k0 + kg * 8];
            const bf16x8 bfr = *(const bf16x8*)(Wh2I + (size_t)arow * 256 + k0 + kg * 8);
            a2 = __builtin_amdgcn_mfma_f32_16x16x32_bf16(afr, bfr, a2, 0,0,0);
        }
        const int col = lane & 15, orow = (lane >> 4) * 4;
        const float bv = bh2[col];
        #pragma unroll
        for (int r = 0; r < 4; ++r)
            outA[(size_t)(node0 + nbase + orow + r) * 16 + col] = a2[r] + bv;
    }
}

// ---------------------------------------------------------------------------
extern "C" void kernel_launch(void* const* d_in, const int* in_sizes, int n_in,
                              void* d_out, int out_size, void* d_ws, size_t ws_size,
                              hipStream_t stream) {
    const float* x   = (const float*)d_in[0];
    const float* z   = (const float*)d_in[1];
    const float* rot = (const float*)d_in[2];
    const float* ea  = (const float*)d_in[4];
    const float* Wam = (const float*)d_in[6];
    const float* bam = (const float*)d_in[7];
    const float* Wbm = (const float*)d_in[8];
    const float* bbm = (const float*)d_in[9];
    const float* gW1 = (const float*)d_in[10];
    const float* gb1 = (const float*)d_in[11];
    const float* gW2 = (const float*)d_in[12];
    const float* gb2 = (const float*)d_in[13];
    const float* Wh1 = (const float*)d_in[14];
    const float* bh1 = (const float*)d_in[15];
    const float* Wh2 = (const float*)d_in[16];
    const float* bh2 = (const float*)d_in[17];
    const float* We1 = (const float*)d_in[18];
    const float* be1 = (const float*)d_in[19];
    const float* We2 = (const float*)d_in[20];
    const float* be2 = (const float*)d_in[21];
    float* out = (float*)d_out;

    float* ws  = (float*)d_ws;
    float* s    = ws;                       // 8192*256 fp32
    float* pos  = ws + 2097152;             // 8192*3
    short* e    = (short*)(ws + 2121728);   // 8192*31*32 bf16
    short* wb   = (short*)(ws + 6184960);   // weight images
    short* sbf0 = (short*)(ws + 6774784);   // 8192*256 bf16

    init_all<<<1536, 256, 0, stream>>>(x, z, rot, Wam, bam, ea, Wbm, bbm,
        gW1, gW2, Wh1, We1, We2, Wh2, s, sbf0, pos, e, wb);

    mol_layers<<<N_MOLS, 1024, 0, stream>>>(sbf0, pos, e, wb, gb1, gb2, s);

    bond_mfma<<<2 * N_MOLS, 512, 0, stream>>>(
        sbf0, wb + OFF_WE1T, pos, e, wb + OFF_WE1CG, wb + OFF_WD,
        wb + OFF_WE2I, wb + OFF_WH1T, wb + OFF_WH2T,
        be1, be2, bh1, bh2, out, out + 131072, out + 131072 + 1269760);
}

// Round 12
// 580.075 us; speedup vs baseline: 2.2460x; 2.2460x over previous
//
#include <hip/hip_runtime.h>
#include <hip/hip_bf16.h>
#include <cstdint>
#include <cstddef>

#define N_MOLS 256
#define NN     8192
#define SDIM_  256
#define NAF_   16
#define LAYERS_ 5

typedef __attribute__((ext_vector_type(8)))  short bf16x8;
typedef __attribute__((ext_vector_type(16))) float f32x16;
typedef __attribute__((ext_vector_type(4)))  float f32x4;

// fast silu: v_rcp instead of IEEE divide (~13 -> ~5 VALU ops; rounded to bf16
// downstream so the 1-ulp rcp error is invisible).
__device__ __forceinline__ float silu_f(float x) {
    return x * __builtin_amdgcn_rcpf(1.f + __expf(-x));
}
__device__ __forceinline__ short bfc(float f) {
    __hip_bfloat16 h = __float2bfloat16(f);
    return __builtin_bit_cast(short, h);
}
__device__ __forceinline__ float bf2f(short h) {
    union { uint32_t u; float f; } v; v.u = ((uint32_t)(unsigned short)h) << 16; return v.f;
}
#define ONEBF ((short)0x3F80)

// ---------------------------------------------------------------------------
// weight image offsets (in shorts, within wb)
// ---------------------------------------------------------------------------
#define OFF_T1    0         // 5 * 512*256   : W1ab^T  [l][j2][k]
#define OFF_W2ST  655360    // 5 * 256*256   : W2s^T   [l][n][k]
#define OFF_WH1T  983040    // 256*256       : Wh1^T   [n][k]
#define OFF_WE1T  1048576   // 128*256       : We1^T   [n][k]
#define OFF_W1CG  1081344   // 5 * 256*32    : W1c slot groups [l][j][w]
#define OFF_W1DA  1122304   // 5 * 2*256    : W1 d/a rows
#define OFF_W2P   1124864   // 5 * 256       : W2 col 320
#define OFF_W2EI  1126144   // 5 * 8192      : sW2e fragment image
#define OFF_WE1CG 1167104   // 128*32        : We1c slot groups
#define OFF_WD    1171200   // 128           : We1 row 288
#define OFF_WE2I  1171328   // 8*64*8        : We2 fragment image
#define OFF_WH2T  1175424   // 16*256        : Wh2^T [n=16][k=256]
#define W_TOTAL   1179520

// ---------------------------------------------------------------------------
// merged init: blocks [0,1024) weight images; [1024,1280) node init;
// [1280,1536) edge init. All three independent.
// ---------------------------------------------------------------------------
__global__ __launch_bounds__(256) void init_all(
    const float* __restrict__ x, const float* __restrict__ z,
    const float* __restrict__ rot, const float* __restrict__ Wam,
    const float* __restrict__ bam, const float* __restrict__ ea,
    const float* __restrict__ Wbm, const float* __restrict__ bbm,
    const float* __restrict__ gW1, const float* __restrict__ gW2,
    const float* __restrict__ Wh1, const float* __restrict__ We1,
    const float* __restrict__ We2, const float* __restrict__ Wh2,
    float* __restrict__ s, short* __restrict__ sbf, float* __restrict__ pos,
    short* __restrict__ ebuf, short* __restrict__ wb)
{
    __shared__ __align__(16) char smem[20608];
    const int b = blockIdx.x, t = threadIdx.x;
    if (b < 1024) {
        for (int o = b * 256 + t; o < W_TOTAL; o += 1024 * 256) {
            float v;
            if (o < OFF_W2ST) {                       // T1 [l][j2<512][k<256]
                const int l = o >> 17, r = o & 131071;
                const int j2 = r >> 8, k = r & 255;
                v = gW1[(size_t)l * 139776 + (size_t)((j2 >> 8) * 256 + k) * 256 + (j2 & 255)];
            } else if (o < OFF_WH1T) {                // W2sT [l][n][k]
                const int q = o - OFF_W2ST;
                const int l = q >> 16, r = q & 65535;
                const int n = r >> 8, k = r & 255;
                v = gW2[(size_t)l * 90368 + (size_t)k * 353 + n];
            } else if (o < OFF_WE1T) {                // Wh1T [n][k]
                const int q = o - OFF_WH1T;
                v = Wh1[(size_t)(q & 255) * 256 + (q >> 8)];
            } else if (o < OFF_W1CG) {                // We1T [n][k]
                const int q = o - OFF_WE1T;
                v = We1[(size_t)(q & 255) * 128 + (q >> 8)];
            } else if (o < OFF_W1DA) {                // W1cG [l][j][w]
                const int q = o - OFF_W1CG;
                const int l = q >> 13, r = q & 8191;
                const int j = r >> 5, w = r & 31;
                v = gW1[(size_t)l * 139776 + (size_t)(512 + w) * 256 + j];
            } else if (o < OFF_W2P) {                 // W1da [l][d][j]
                const int q = o - OFF_W1DA;
                const int l = q >> 9, r = q & 511;
                v = gW1[(size_t)l * 139776 + (size_t)(544 + (r >> 8)) * 256 + (r & 255)];
            } else if (o < OFF_W2EI) {                // W2p [l][j]
                const int q = o - OFF_W2P;
                v = gW2[(size_t)(q >> 8) * 90368 + (size_t)(q & 255) * 353 + 320];
            } else if (o < OFF_WE1CG) {               // W2e fragment image [l][idx]
                const int q = o - OFF_W2EI;
                const int l = q >> 13, r = q & 8191;
                const int kk = r >> 9, lanei = (r >> 3) & 63, jj = r & 7;
                const int j = kk * 16 + (lanei >> 5) * 8 + jj;
                v = gW2[(size_t)l * 90368 + (size_t)j * 353 + 321 + (lanei & 31)];
            } else if (o < OFF_WD) {                  // We1cG [j][w]
                const int q = o - OFF_WE1CG;
                v = We1[(size_t)(256 + (q & 31)) * 128 + (q >> 5)];
            } else if (o < OFF_WE2I) {                // Wd [j]
                v = We1[288 * 128 + (o - OFF_WD)];
            } else if (o < OFF_WH2T) {                // We2 fragment image
                const int q = o - OFF_WE2I;
                const int kk = q >> 9, lanei = (q >> 3) & 63, jj = q & 7;
                const int c = lanei & 31;
                v = (c < 5) ? We2[(size_t)(kk * 16 + (lanei >> 5) * 8 + jj) * 5 + c] : 0.f;
            } else {                                  // Wh2T [n=16][k=256]
                const int q = o - OFF_WH2T;
                v = Wh2[(size_t)(q & 255) * 16 + (q >> 8)];
            }
            wb[o] = bfc(v);
        }
    } else if (b < 1280) {
        // ---- node init: h = [x|z]@Wam+bam; s, sbf, pos
        const int mol = b - 1024;
        float (*xz)[80]  = (float(*)[80])smem;
        float (*praw)[3] = (float(*)[3])(smem + 32 * 80 * 4);
        for (int idx = t; idx < 32 * 80; idx += 256) {
            const int i = idx / 80, k = idx % 80;
            xz[i][k] = (k < 16) ? x[(size_t)(mol * 32 + i) * 16 + k]
                                : z[(size_t)(mol * 32 + i) * 64 + (k - 16)];
        }
        __syncthreads();
        float acc[32];
        #pragma unroll
        for (int i = 0; i < 32; ++i) acc[i] = 0.f;
        for (int k0 = 0; k0 < 80; k0 += 4) {
            const float w0 = Wam[(k0 + 0) * 259 + t];
            const float w1 = Wam[(k0 + 1) * 259 + t];
            const float w2 = Wam[(k0 + 2) * 259 + t];
            const float w3 = Wam[(k0 + 3) * 259 + t];
            #pragma unroll
            for (int i = 0; i < 32; ++i) {
                const float4 xv = *(const float4*)&xz[i][k0];
                acc[i] += xv.x * w0 + xv.y * w1 + xv.z * w2 + xv.w * w3;
            }
        }
        const float bv = bam[t];
        #pragma unroll
        for (int i = 0; i < 32; ++i) {
            const float v = acc[i] + bv;
            s[(size_t)(mol * 32 + i) * 256 + t] = v;
            sbf[(size_t)(mol * 32 + i) * 256 + t] = bfc(v);
        }
        if (t < 96) {
            const int i = t / 3, c = t % 3;
            float a2 = bam[256 + c];
            for (int k = 0; k < 80; ++k) a2 += xz[i][k] * Wam[k * 259 + 256 + c];
            praw[i][c] = a2;
        }
        __syncthreads();
        if (t < 96) {
            const int i = t / 3, c = t % 3;
            float p = 0.f;
            for (int jj = 0; jj < 3; ++jj) p += rot[mol * 9 + c * 3 + jj] * praw[i][jj];
            pos[(size_t)(mol * 32 + i) * 3 + c] = p;
        }
    } else {
        // ---- edge init (LDS-staged ea, 1 block/mol)
        const int mol = b - 1280;
        float* sEa      = (float*)smem;
        float (*sW)[32] = (float(*)[32])(smem + 4960 * 4);
        float* sB       = (float*)(smem + (4960 + 160) * 4);
        const float* base = ea + (size_t)mol * 4960;
        for (int i = t; i < 4960; i += 256) sEa[i] = base[i];
        if (t < 160) sW[t / 32][t & 31] = Wbm[t];
        if (t < 32)  sB[t] = bbm[t];
        __syncthreads();
        for (int i = t; i < 31744; i += 256) {
            const int c = i & 31;
            const int rrn = i >> 5;
            const int n = rrn / 31, rr = rrn - n * 31;
            const int s_ = rr + (rr >= n ? 1 : 0);
            const int gl = s_ * 31 + (n - (n > s_ ? 1 : 0));
            float acc = sB[c];
            #pragma unroll
            for (int k = 0; k < 5; ++k) acc += sEa[gl * 5 + k] * sW[k][c];
            ebuf[(size_t)mol * 31744 + i] = bfc(acc);
        }
    }
}

// ---------------------------------------------------------------------------
// MFMA edge kernel with fused dual-GEMM prologue and s-update epilogue.
// Grid 512 (2/mol), 512 thr. == r9 verbatim (measured 583.5us total) ==
// OCCUPANCY-ALLOCATOR LESSON (r4/r10/r11): any explicit occupancy hint
// (__launch_bounds__(N,waves) or amdgpu_waves_per_eu) makes the allocator
// pick VGPR=64 for these bodies -> ~2.7GB scratch spill, 2.2x regression.
// A 1024-thr 5-layer merged variant is structurally sound but blocked on
// this. Only plain __launch_bounds__(512) reliably compiles at VGPR=128.
// ---------------------------------------------------------------------------
__global__ __launch_bounds__(512) void edge_mfma(
    const short* __restrict__ sbfA, const short* __restrict__ T1,
    const float* __restrict__ posIn, float* __restrict__ posOut,
    short* __restrict__ ebuf,
    const short* __restrict__ W1cG, const short* __restrict__ W1daP,
    const short* __restrict__ W2pP, const short* __restrict__ W2eimg,
    const short* __restrict__ W2sT,
    const float* __restrict__ b1, const float* __restrict__ b2,
    float* __restrict__ s, short* __restrict__ sbfOut)
{
    const int blk = blockIdx.x;
    const int mol = blk >> 1;
    const int nbase = (blk & 1) * 16;
    const int t = threadIdx.x;
    const int wave = t >> 6, lane = t & 63;
    const int l = lane & 31, half = lane >> 5;
    const int node0 = mol * 32;

    __shared__ __align__(16) short sBg[256][72];      // 36 KB
    __shared__ __align__(16) short sM[8][32][40];     // 20 KB union: phase0 = sSbf[32][264]
    __shared__ __align__(16) short sHrows[16][264];   // 8.25 KB
    __shared__ __align__(16) short sSB[16][264];      // 8.25 KB
    __shared__ float sPosS[32][4];
    __shared__ __align__(16) short sW1da[2][256];
    __shared__ __align__(16) short sW2p[256];
    __shared__ float sP[8][32];
    __shared__ float sPd[16][4];
    short* sSbf = &sM[0][0][0];   // [32][264] view, phase0 only

    // ---- phase 0a: stage W1c (pre-swizzled image), sbf block, small tables
    {
        const int j = t & 255, gh = t >> 8;
        const bf16x8 v0 = *(const bf16x8*)&W1cG[j * 32 + gh * 16];
        const bf16x8 v1 = *(const bf16x8*)&W1cG[j * 32 + gh * 16 + 8];
        const int c3 = (j >> 3) & 3;
        const int s0 = ((gh * 2 + 0) + 3 * c3) & 7;
        const int s1 = ((gh * 2 + 1) + 3 * c3) & 7;
        *(bf16x8*)&sBg[j][s0 * 8] = v0;
        *(bf16x8*)&sBg[j][s1 * 8] = v1;
    }
    {   // sbf rows -> sSbf (padded rows of 264)
        const int row = t >> 4, ch = (t & 15) * 16;
        const short* src = sbfA + (size_t)(node0 + row) * 256 + ch;
        *(bf16x8*)&sSbf[row * 264 + ch]     = *(const bf16x8*)(src);
        *(bf16x8*)&sSbf[row * 264 + ch + 8] = *(const bf16x8*)(src + 8);
    }
    if (t < 64) {
        short* d = &sW1da[0][0];
        *(bf16x8*)&d[t * 8] = *(const bf16x8*)&W1daP[t * 8];
    }
    if (t < 32) *(bf16x8*)&sW2p[t * 8] = *(const bf16x8*)&W2pP[t * 8];
    if (t < 96) sPosS[t / 3][t % 3] = posIn[node0 * 3 + t];
    __syncthreads();

    // ---- phase 0b: dual GEMM (SA -> sBg k32..63 swizzled; SB -> sSB)
    {
        const int jt = wave;                // col-tile per wave
        const int j = jt * 32 + l;
        f32x16 accA = {}, accB = {};
        #pragma unroll
        for (int k0 = 0; k0 < 256; k0 += 16) {
            const bf16x8 afr = *(const bf16x8*)&sSbf[l * 264 + k0 + half * 8];
            const bf16x8 bA  = *(const bf16x8*)(T1 + (size_t)(j) * 256 + k0 + half * 8);
            const bf16x8 bB  = *(const bf16x8*)(T1 + (size_t)(256 + j) * 256 + k0 + half * 8);
            accA = __builtin_amdgcn_mfma_f32_32x32x16_bf16(afr, bA, accA, 0,0,0);
            accB = __builtin_amdgcn_mfma_f32_32x32x16_bf16(afr, bB, accB, 0,0,0);
        }
        const int c3 = (j >> 3) & 3;
        #pragma unroll
        for (int r = 0; r < 16; ++r) {
            const int node = (r & 3) + 8 * (r >> 2) + 4 * half;
            const int k = 32 + node;
            const int slot = ((k >> 3) + 3 * c3) & 7;
            sBg[j][slot * 8 + (k & 7)] = bfc(accA[r]);
            const int nl = node - nbase;
            if ((unsigned)nl < 16u) sSB[nl][j] = bfc(accB[r]);
        }
    }
    __syncthreads();

    float b1v[8];
    short w1dv[8], w1av[8];
    #pragma unroll
    for (int cb = 0; cb < 8; ++cb) {
        b1v[cb]  = b1[cb * 32 + l];
        w1dv[cb] = sW1da[0][cb * 32 + l];
        w1av[cb] = sW1da[1][cb * 32 + l];
    }
    const float b2e = b2[321 + l];
    const float b2p = b2[320];
    int bslot[4];
    #pragma unroll
    for (int ks = 0; ks < 4; ++ks)
        bslot[ks] = ((ks * 2 + half) + 3 * ((l >> 3) & 3)) & 7;

    // prefetch ebuf fragments for BOTH ni iterations (hide latency under ni=0)
    bf16x8 efr0[2], efr1[2];
    #pragma unroll
    for (int ni = 0; ni < 2; ++ni) {
        const int n = nbase + wave + ni * 8;
        const short* ebase = ebuf + ((size_t)((mol * 32 + n) * 31 + l)) * 32;
        efr0[ni] = *(const bf16x8*)(ebase + half * 8);
        efr1[ni] = *(const bf16x8*)(ebase + 16 + half * 8);
    }

    // ---- phase 1: edge messages
    #pragma unroll
    for (int ni = 0; ni < 2; ++ni) {
        const int n = nbase + wave + ni * 8;
        const int nloc = wave + ni * 8;
        const int rrc = (l < 31) ? l : 30;
        const int src = rrc + (rrc >= n ? 1 : 0);
        const float ax = sPosS[n][0],  ay = sPosS[n][1],  az = sPosS[n][2];
        const float bx = sPosS[src][0], by = sPosS[src][1], bz = sPosS[src][2];
        const float rx = ax - bx, ry = ay - by, rz = az - bz;
        const float av = ax * bx + ay * by + az * bz;
        const float dd = sqrtf(fmaxf(rx * rx + ry * ry + rz * rz, 1e-6f));
        const float inv = __builtin_amdgcn_rcpf(1.f + dd);
        const float rnx = rx * inv, rny = ry * inv, rnz = rz * inv;

        const bf16x8 fr0 = efr0[ni];
        const bf16x8 fr1 = efr1[ni];
        bf16x8 fr2 = {}, fr3, fr4;
        if (half == 0) { fr2[0] = bfc(dd); fr2[1] = bfc(av); }
        #pragma unroll
        for (int jj = 0; jj < 8; ++jj) {
            fr3[jj] = (half * 8 + jj == src)      ? ONEBF : (short)0;
            fr4[jj] = (16 + half * 8 + jj == src) ? ONEBF : (short)0;
        }

        // opaque per-ni view of the W2e image: prevents cross-ni CSE/hoist of
        // the per-cb fragment loads back into 64 resident VGPRs.
        const short* W2ei = W2eimg;
        asm volatile("" : "+s"(W2ei));

        f32x16 accC = {}, accP = {};
        float Hacc[8];

        const int g = l >> 3, jlow = l & 7;
        #pragma unroll
        for (int cb = 0; cb < 8; ++cb) {
            // per-cb W2e fragments (L2-hot, issued before the MFMA cluster)
            const bf16x8 w2e0 = *(const bf16x8*)&W2ei[(size_t)((cb * 2 + 0) * 64 + lane) * 8];
            const bf16x8 w2e1 = *(const bf16x8*)&W2ei[(size_t)((cb * 2 + 1) * 64 + lane) * 8];
            const float sbv = bf2f(sSB[nloc][cb * 32 + l]) + b1v[cb];
            f32x16 acc;
            #pragma unroll
            for (int r = 0; r < 16; ++r) acc[r] = sbv;
            {
                const short* brow = &sBg[cb * 32 + l][0];
                __builtin_amdgcn_s_setprio(1);
                acc = __builtin_amdgcn_mfma_f32_32x32x16_bf16(fr0, *(const bf16x8*)(brow + bslot[0]*8), acc, 0,0,0);
                acc = __builtin_amdgcn_mfma_f32_32x32x16_bf16(fr1, *(const bf16x8*)(brow + bslot[1]*8), acc, 0,0,0);
                acc = __builtin_amdgcn_mfma_f32_32x32x16_bf16(fr3, *(const bf16x8*)(brow + bslot[2]*8), acc, 0,0,0);
                acc = __builtin_amdgcn_mfma_f32_32x32x16_bf16(fr4, *(const bf16x8*)(brow + bslot[3]*8), acc, 0,0,0);
                bf16x8 frB2 = {};
                if (half == 0) { frB2[0] = w1dv[cb]; frB2[1] = w1av[cb]; }
                acc = __builtin_amdgcn_mfma_f32_32x32x16_bf16(fr2, frB2, acc, 0,0,0);
                __builtin_amdgcn_s_setprio(0);
            }
            float hs = 0.f;
            #pragma unroll
            for (int r = 0; r < 16; ++r) {
                const int e = (r & 3) + 8 * (r >> 2) + 4 * half;
                float h = silu_f(acc[r]);
                if (half == 1 && r == 15) h = 0.f;   // pad row 31
                hs += h;
                sM[wave][e][((g + (e >> 3)) & 3) * 8 + jlow] = bfc(h);
            }
            Hacc[cb] = hs;
            #pragma unroll
            for (int q = 0; q < 2; ++q) {
                const bf16x8 afr  = *(const bf16x8*)&sM[wave][l][((q * 2 + half + (l >> 3)) & 3) * 8];
                const bf16x8 wpfr = *(const bf16x8*)&sW2p[cb * 32 + q * 16 + half * 8];
                accC = __builtin_amdgcn_mfma_f32_32x32x16_bf16(afr, q ? w2e1 : w2e0, accC, 0,0,0);
                accP = __builtin_amdgcn_mfma_f32_32x32x16_bf16(afr, wpfr, accP, 0,0,0);
            }
        }
        // H row into LDS tile (bf16)
        #pragma unroll
        for (int cb = 0; cb < 8; ++cb) {
            const float v = Hacc[cb] + __shfl_xor(Hacc[cb], 32, 64);
            if (lane < 32) sHrows[nloc][cb * 32 + lane] = bfc(v);
        }
        // p: accP cols all equal; lanes l==0 (both halves) scatter 16 rows each
        if (l == 0) {
            #pragma unroll
            for (int q4 = 0; q4 < 4; ++q4) {
                float4 pv = { accP[q4 * 4 + 0], accP[q4 * 4 + 1],
                              accP[q4 * 4 + 2], accP[q4 * 4 + 3] };
                *(float4*)&sP[wave][q4 * 8 + 4 * half] = pv;
            }
        }
        const float pown = sP[wave][l];
        const float pfull = (half == 0 && l < 31) ? (pown + b2p) : 0.f;
        float pd0 = rnx * pfull, pd1 = rny * pfull, pd2 = rnz * pfull;
        #pragma unroll
        for (int m = 1; m <= 32; m <<= 1) {
            pd0 += __shfl_xor(pd0, m, 64);
            pd1 += __shfl_xor(pd1, m, 64);
            pd2 += __shfl_xor(pd2, m, 64);
        }
        if (lane == 0) {
            sPd[nloc][0] = pd0;
            sPd[nloc][1] = pd1;
            sPd[nloc][2] = pd2;
        }
        // e update (bf16 RMW)
        #pragma unroll
        for (int r = 0; r < 16; ++r) {
            const int e = (r & 3) + 8 * (r >> 2) + 4 * half;
            if (e < 31) {
                short* ep = ebuf + ((size_t)((mol * 32 + n) * 31 + e)) * 32 + l;
                *ep = bfc(bf2f(*ep) + accC[r] + b2e);
            }
        }
    }

    __syncthreads();  // H-tile + sPd complete

    // ---- phase 2: s-update via 16x16x32 MFMA (16 rows, no padding)
    {
        const int jb0 = wave * 32;
        const int arow = lane & 15, kg = lane >> 4;   // kg in 0..3
        f32x4 accS0 = {}, accS1 = {};
        #pragma unroll
        for (int k0 = 0; k0 < 256; k0 += 32) {
            const bf16x8 afr = *(const bf16x8*)&sHrows[arow][k0 + kg * 8];
            const bf16x8 bf0 = *(const bf16x8*)&W2sT[(size_t)(jb0 + arow) * 256 + k0 + kg * 8];
            const bf16x8 bf1 = *(const bf16x8*)&W2sT[(size_t)(jb0 + 16 + arow) * 256 + k0 + kg * 8];
            accS0 = __builtin_amdgcn_mfma_f32_16x16x32_bf16(afr, bf0, accS0, 0,0,0);
            accS1 = __builtin_amdgcn_mfma_f32_16x16x32_bf16(afr, bf1, accS1, 0,0,0);
        }
        const int col = lane & 15;
        const int orow = (lane >> 4) * 4;
        const float bv0 = b2[jb0 + col];
        const float bv1 = b2[jb0 + 16 + col];
        #pragma unroll
        for (int r = 0; r < 4; ++r) {
            const int node = node0 + nbase + orow + r;
            {
                float* sp = s + (size_t)node * 256 + jb0 + col;
                const float nv = *sp + accS0[r] * (1.f / 31.f) + bv0;
                *sp = nv;
                sbfOut[(size_t)node * 256 + jb0 + col] = bfc(nv);
            }
            {
                float* sp = s + (size_t)node * 256 + jb0 + 16 + col;
                const float nv = *sp + accS1[r] * (1.f / 31.f) + bv1;
                *sp = nv;
                sbfOut[(size_t)node * 256 + jb0 + 16 + col] = bfc(nv);
            }
        }
    }
    // pos update
    if (t < 48) {
        const int nl = t / 3, c = t % 3;
        const int node = node0 + nbase + nl;
        posOut[(size_t)node * 3 + c] = posIn[(size_t)node * 3 + c] + sPd[nl][c] * (1.f / 31.f);
    }
}

// ---------------------------------------------------------------------------
// MFMA bond kernel: fused U-GEMM prologue, atoms epilogue (silu(s@Wh1)@Wh2),
// and pos output copy. Grid 512, 512 thr.
// ---------------------------------------------------------------------------
__global__ __launch_bounds__(512) void bond_mfma(
    const short* __restrict__ sbfA, const short* __restrict__ We1T,
    const float* __restrict__ pos, short* __restrict__ ebuf,
    const short* __restrict__ We1cG, const short* __restrict__ WdP,
    const short* __restrict__ We2img, const short* __restrict__ Wh1T,
    const short* __restrict__ Wh2I,
    const float* __restrict__ be1, const float* __restrict__ be2,
    const float* __restrict__ bh1, const float* __restrict__ bh2,
    float* __restrict__ outA, float* __restrict__ outB,
    float* __restrict__ outPos)
{
    const int blk = blockIdx.x;
    const int mol = blk >> 1;
    const int nbase = (blk & 1) * 16;
    const int t = threadIdx.x;
    const int wave = t >> 6, lane = t & 63;
    const int l = lane & 31, half = lane >> 5;
    const int node0 = mol * 32;

    __shared__ __align__(16) short sBg2[128][72];
    __shared__ __align__(16) short sHdnB[8][32][40];
    __shared__ __align__(16) short sU[32][136];
    __shared__ float sPosS[32][4];
    __shared__ __align__(16) short sWd[128];
    short* sSbf = &sHdnB[0][0][0];   // [32][264] view, phase0 only

    {
        const int j = t & 127, g = t >> 7;
        const bf16x8 v = *(const bf16x8*)&We1cG[j * 32 + g * 8];
        const int slot = (g + 3 * ((j >> 3) & 3)) & 7;
        *(bf16x8*)&sBg2[j][slot * 8] = v;
    }
    {
        const int row = t >> 4, ch = (t & 15) * 16;
        const short* src = sbfA + (size_t)(node0 + row) * 256 + ch;
        *(bf16x8*)&sSbf[row * 264 + ch]     = *(const bf16x8*)(src);
        *(bf16x8*)&sSbf[row * 264 + ch + 8] = *(const bf16x8*)(src + 8);
    }
    if (t < 16) *(bf16x8*)&sWd[t * 8] = *(const bf16x8*)&WdP[t * 8];
    if (t < 96) sPosS[t / 3][t % 3] = pos[node0 * 3 + t];
    __syncthreads();

    if (wave < 4) {
        const int j = wave * 32 + l;
        f32x16 accU = {};
        #pragma unroll
        for (int k0 = 0; k0 < 256; k0 += 16) {
            const bf16x8 afr = *(const bf16x8*)&sSbf[l * 264 + k0 + half * 8];
            const bf16x8 bU  = *(const bf16x8*)(We1T + (size_t)j * 256 + k0 + half * 8);
            accU = __builtin_amdgcn_mfma_f32_32x32x16_bf16(afr, bU, accU, 0,0,0);
        }
        const int c3 = (j >> 3) & 3;
        #pragma unroll
        for (int r = 0; r < 16; ++r) {
            const int node = (r & 3) + 8 * (r >> 2) + 4 * half;
            const short uv = bfc(accU[r]);
            const int k = 32 + node;
            const int slot = ((k >> 3) + 3 * c3) & 7;
            sBg2[j][slot * 8 + (k & 7)] = uv;
            sU[node][j] = uv;
        }
    }

    float be1v[4];
    #pragma unroll
    for (int cb = 0; cb < 4; ++cb) be1v[cb] = be1[cb * 32 + l];
    const float be2v = (l < 5) ? be2[l] : 0.f;
    int bslot[4];
    #pragma unroll
    for (int ks = 0; ks < 4; ++ks)
        bslot[ks] = ((ks * 2 + half) + 3 * ((l >> 3) & 3)) & 7;
    __syncthreads();

    bf16x8 efr0[2], efr1[2];
    #pragma unroll
    for (int ni = 0; ni < 2; ++ni) {
        const int n = nbase + wave + ni * 8;
        const short* ebase = ebuf + ((size_t)((mol * 32 + n) * 31 + l)) * 32;
        efr0[ni] = *(const bf16x8*)(ebase + half * 8);
        efr1[ni] = *(const bf16x8*)(ebase + 16 + half * 8);
    }

    #pragma unroll
    for (int ni = 0; ni < 2; ++ni) {
        const int n = nbase + wave + ni * 8;
        const int rrc = (l < 31) ? l : 30;
        const int src = rrc + (rrc >= n ? 1 : 0);
        const float rx = sPosS[n][0] - sPosS[src][0];
        const float ry = sPosS[n][1] - sPosS[src][1];
        const float rz = sPosS[n][2] - sPosS[src][2];
        const float dd = sqrtf(fmaxf(rx * rx + ry * ry + rz * rz, 1e-6f));

        const bf16x8 fr0 = efr0[ni];
        const bf16x8 fr1 = efr1[ni];
        bf16x8 fr2 = {}, fr3, fr4;
        if (half == 0) fr2[0] = bfc(dd);
        #pragma unroll
        for (int jj = 0; jj < 8; ++jj) {
            fr3[jj] = (half * 8 + jj == src)      ? ONEBF : (short)0;
            fr4[jj] = (16 + half * 8 + jj == src) ? ONEBF : (short)0;
        }

        const short* We2i = We2img;
        asm volatile("" : "+s"(We2i));

        f32x16 accC = {};
        const int g = l >> 3, jlow = l & 7;
        #pragma unroll
        for (int cb = 0; cb < 4; ++cb) {
            const bf16x8 w2f0 = *(const bf16x8*)&We2i[(size_t)((cb * 2 + 0) * 64 + lane) * 8];
            const bf16x8 w2f1 = *(const bf16x8*)&We2i[(size_t)((cb * 2 + 1) * 64 + lane) * 8];
            const float uin = bf2f(sU[n][cb * 32 + l]) + be1v[cb];
            f32x16 acc;
            #pragma unroll
            for (int r = 0; r < 16; ++r) acc[r] = uin;
            {
                const short* brow = &sBg2[cb * 32 + l][0];
                acc = __builtin_amdgcn_mfma_f32_32x32x16_bf16(fr0, *(const bf16x8*)(brow + bslot[0]*8), acc, 0,0,0);
                acc = __builtin_amdgcn_mfma_f32_32x32x16_bf16(fr1, *(const bf16x8*)(brow + bslot[1]*8), acc, 0,0,0);
                acc = __builtin_amdgcn_mfma_f32_32x32x16_bf16(fr3, *(const bf16x8*)(brow + bslot[2]*8), acc, 0,0,0);
                acc = __builtin_amdgcn_mfma_f32_32x32x16_bf16(fr4, *(const bf16x8*)(brow + bslot[3]*8), acc, 0,0,0);
                bf16x8 frWd = {};
                if (half == 0) frWd[0] = sWd[cb * 32 + l];
                acc = __builtin_amdgcn_mfma_f32_32x32x16_bf16(fr2, frWd, acc, 0,0,0);
            }
            #pragma unroll
            for (int r = 0; r < 16; ++r) {
                const int e = (r & 3) + 8 * (r >> 2) + 4 * half;
                sHdnB[wave][e][((g + (e >> 3)) & 3) * 8 + jlow] = bfc(silu_f(acc[r]));
            }
            #pragma unroll
            for (int q = 0; q < 2; ++q) {
                const bf16x8 afr = *(const bf16x8*)&sHdnB[wave][l][((q * 2 + half + (l >> 3)) & 3) * 8];
                accC = __builtin_amdgcn_mfma_f32_32x32x16_bf16(afr, q ? w2f1 : w2f0, accC, 0,0,0);
            }
        }
        if (l < 5) {
            #pragma unroll
            for (int r = 0; r < 16; ++r) {
                const int e = (r & 3) + 8 * (r >> 2) + 4 * half;
                if (e < 31) {
                    const int s_ = e + (e >= n ? 1 : 0);
                    const int ge = (mol * 32 + s_) * 31 + (n - (n > s_ ? 1 : 0));
                    outB[(size_t)ge * 5 + l] = accC[r] + be2v;
                }
            }
        }
    }
    if (t < 48) {
        const int nl = t / 3, c = t % 3;
        const int node = node0 + nbase + nl;
        outPos[(size_t)node * 3 + c] = pos[(size_t)node * 3 + c];
    }

    // ---- phase 3: atoms
    __syncthreads();
    {
        short* sA3 = &sU[0][0];
        const int row = t >> 5, ch = (t & 31) * 8;
        *(bf16x8*)&sA3[row * 264 + ch] =
            *(const bf16x8*)(sbfA + (size_t)(node0 + nbase + row) * 256 + ch);
    }
    __syncthreads();
    {
        short* sA3 = &sU[0][0];
        short* sT  = &sBg2[0][0];
        const int jb0 = wave * 32;
        const int arow = lane & 15, kg = lane >> 4;
        f32x4 a0 = {}, a1 = {};
        #pragma unroll
        for (int k0 = 0; k0 < 256; k0 += 32) {
            const bf16x8 afr = *(const bf16x8*)&sA3[arow * 264 + k0 + kg * 8];
            const bf16x8 bw0 = *(const bf16x8*)(Wh1T + (size_t)(jb0 + arow) * 256 + k0 + kg * 8);
            const bf16x8 bw1 = *(const bf16x8*)(Wh1T + (size_t)(jb0 + 16 + arow) * 256 + k0 + kg * 8);
            a0 = __builtin_amdgcn_mfma_f32_16x16x32_bf16(afr, bw0, a0, 0,0,0);
            a1 = __builtin_amdgcn_mfma_f32_16x16x32_bf16(afr, bw1, a1, 0,0,0);
        }
        const int col = lane & 15, orow = (lane >> 4) * 4;
        const float bva = bh1[jb0 + col], bvb = bh1[jb0 + 16 + col];
        #pragma unroll
        for (int r = 0; r < 4; ++r) {
            sT[(orow + r) * 264 + jb0 + col]      = bfc(silu_f(a0[r] + bva));
            sT[(orow + r) * 264 + jb0 + 16 + col] = bfc(silu_f(a1[r] + bvb));
        }
    }
    __syncthreads();
    if (wave == 0) {
        short* sT = &sBg2[0][0];
        const int arow = lane & 15, kg = lane >> 4;
        f32x4 a2 = {};
        #pragma unroll
        for (int k0 = 0; k0 < 256; k0 += 32) {
            const bf16x8 afr = *(const bf16x8*)&sT[arow * 264 + k0 + kg * 8];
            const bf16x8 bfr = *(const bf16x8*)(Wh2I + (size_t)arow * 256 + k0 + kg * 8);
            a2 = __builtin_amdgcn_mfma_f32_16x16x32_bf16(afr, bfr, a2, 0,0,0);
        }
        const int col = lane & 15, orow = (lane >> 4) * 4;
        const float bv = bh2[col];
        #pragma unroll
        for (int r = 0; r < 4; ++r)
            outA[(size_t)(node0 + nbase + orow + r) * 16 + col] = a2[r] + bv;
    }
}

// ---------------------------------------------------------------------------
extern "C" void kernel_launch(void* const* d_in, const int* in_sizes, int n_in,
                              void* d_out, int out_size, void* d_ws, size_t ws_size,
                              hipStream_t stream) {
    const float* x   = (const float*)d_in[0];
    const float* z   = (const float*)d_in[1];
    const float* rot = (const float*)d_in[2];
    const float* ea  = (const float*)d_in[4];
    const float* Wam = (const float*)d_in[6];
    const float* bam = (const float*)d_in[7];
    const float* Wbm = (const float*)d_in[8];
    const float* bbm = (const float*)d_in[9];
    const float* gW1 = (const float*)d_in[10];
    const float* gb1 = (const float*)d_in[11];
    const float* gW2 = (const float*)d_in[12];
    const float* gb2 = (const float*)d_in[13];
    const float* Wh1 = (const float*)d_in[14];
    const float* bh1 = (const float*)d_in[15];
    const float* Wh2 = (const float*)d_in[16];
    const float* bh2 = (const float*)d_in[17];
    const float* We1 = (const float*)d_in[18];
    const float* be1 = (const float*)d_in[19];
    const float* We2 = (const float*)d_in[20];
    const float* be2 = (const float*)d_in[21];
    float* out = (float*)d_out;

    float* ws  = (float*)d_ws;
    float* s    = ws;                       // 8192*256 fp32
    float* pos  = ws + 2097152;             // 8192*3 (ping)
    short* e    = (short*)(ws + 2121728);   // 8192*31*32 bf16
    short* wb   = (short*)(ws + 6184960);   // weight images
    short* sbf0 = (short*)(ws + 6774784);   // 8192*256 bf16 (ping)
    short* sbf1 = (short*)(ws + 10248192);  // 8192*256 bf16 (pong)
    float* pos2 = ws + 16539648;            // 8192*3 (pong)

    init_all<<<1536, 256, 0, stream>>>(x, z, rot, Wam, bam, ea, Wbm, bbm,
        gW1, gW2, Wh1, We1, We2, Wh2, s, sbf0, pos, e, wb);

    float* pbuf[2] = { pos, pos2 };
    short* sbb[2] = { sbf0, sbf1 };
    for (int l = 0; l < LAYERS_; ++l) {
        const float* b1 = gb1 + l * 256;
        const float* b2 = gb2 + l * 353;
        edge_mfma<<<2 * N_MOLS, 512, 0, stream>>>(
            sbb[l & 1], wb + OFF_T1 + (size_t)l * 131072,
            pbuf[l & 1], pbuf[(l + 1) & 1], e,
            wb + OFF_W1CG + l * 8192, wb + OFF_W1DA + l * 512,
            wb + OFF_W2P + l * 256, wb + OFF_W2EI + l * 8192,
            wb + OFF_W2ST + (size_t)l * 65536,
            b1, b2, s, sbb[(l + 1) & 1]);
    }
    float* posF = pbuf[LAYERS_ & 1];
    short* sbfF = sbb[LAYERS_ & 1];

    bond_mfma<<<2 * N_MOLS, 512, 0, stream>>>(
        sbfF, wb + OFF_WE1T, posF, e, wb + OFF_WE1CG, wb + OFF_WD,
        wb + OFF_WE2I, wb + OFF_WH1T, wb + OFF_WH2T,
        be1, be2, bh1, bh2, out, out + 131072, out + 131072 + 1269760);
}

// Round 13
// 578.313 us; speedup vs baseline: 2.2528x; 1.0030x over previous
//
#include <hip/hip_runtime.h>
#include <hip/hip_bf16.h>
#include <cstdint>
#include <cstddef>

#define N_MOLS 256
#define NN     8192
#define SDIM_  256
#define NAF_   16
#define LAYERS_ 5

typedef __attribute__((ext_vector_type(8)))  short bf16x8;
typedef __attribute__((ext_vector_type(16))) float f32x16;
typedef __attribute__((ext_vector_type(4)))  float f32x4;

// fast silu: v_rcp instead of IEEE divide (~13 -> ~5 VALU ops; rounded to bf16
// downstream so the 1-ulp rcp error is invisible).
__device__ __forceinline__ float silu_f(float x) {
    return x * __builtin_amdgcn_rcpf(1.f + __expf(-x));
}
__device__ __forceinline__ short bfc(float f) {
    __hip_bfloat16 h = __float2bfloat16(f);
    return __builtin_bit_cast(short, h);
}
__device__ __forceinline__ float bf2f(short h) {
    union { uint32_t u; float f; } v; v.u = ((uint32_t)(unsigned short)h) << 16; return v.f;
}
#define ONEBF ((short)0x3F80)

// ---------------------------------------------------------------------------
// weight image offsets (in shorts, within wb)
// ---------------------------------------------------------------------------
#define OFF_T1    0         // 5 * 512*256   : W1ab^T  [l][j2][k]
#define OFF_W2ST  655360    // 5 * 256*256   : W2s^T   [l][n][k]
#define OFF_WH1T  983040    // 256*256       : Wh1^T   [n][k]
#define OFF_WE1T  1048576   // 128*256       : We1^T   [n][k]
#define OFF_W1CG  1081344   // 5 * 256*32    : W1c slot groups [l][j][w]
#define OFF_W1DA  1122304   // 5 * 2*256    : W1 d/a rows
#define OFF_W2P   1124864   // 5 * 256       : W2 col 320
#define OFF_W2EI  1126144   // 5 * 8192      : sW2e fragment image
#define OFF_WE1CG 1167104   // 128*32        : We1c slot groups
#define OFF_WD    1171200   // 128           : We1 row 288
#define OFF_WE2I  1171328   // 8*64*8        : We2 fragment image
#define OFF_WH2T  1175424   // 16*256        : Wh2^T [n=16][k=256]
#define W_TOTAL   1179520

// ---------------------------------------------------------------------------
// merged init: blocks [0,1024) weight images; [1024,1280) node init;
// [1280,1536) edge init. All three independent.
// ---------------------------------------------------------------------------
__global__ __launch_bounds__(256) void init_all(
    const float* __restrict__ x, const float* __restrict__ z,
    const float* __restrict__ rot, const float* __restrict__ Wam,
    const float* __restrict__ bam, const float* __restrict__ ea,
    const float* __restrict__ Wbm, const float* __restrict__ bbm,
    const float* __restrict__ gW1, const float* __restrict__ gW2,
    const float* __restrict__ Wh1, const float* __restrict__ We1,
    const float* __restrict__ We2, const float* __restrict__ Wh2,
    float* __restrict__ s, short* __restrict__ sbf, float* __restrict__ pos,
    short* __restrict__ ebuf, short* __restrict__ wb)
{
    __shared__ __align__(16) char smem[20608];
    const int b = blockIdx.x, t = threadIdx.x;
    if (b < 1024) {
        for (int o = b * 256 + t; o < W_TOTAL; o += 1024 * 256) {
            float v;
            if (o < OFF_W2ST) {                       // T1 [l][j2<512][k<256]
                const int l = o >> 17, r = o & 131071;
                const int j2 = r >> 8, k = r & 255;
                v = gW1[(size_t)l * 139776 + (size_t)((j2 >> 8) * 256 + k) * 256 + (j2 & 255)];
            } else if (o < OFF_WH1T) {                // W2sT [l][n][k]
                const int q = o - OFF_W2ST;
                const int l = q >> 16, r = q & 65535;
                const int n = r >> 8, k = r & 255;
                v = gW2[(size_t)l * 90368 + (size_t)k * 353 + n];
            } else if (o < OFF_WE1T) {                // Wh1T [n][k]
                const int q = o - OFF_WH1T;
                v = Wh1[(size_t)(q & 255) * 256 + (q >> 8)];
            } else if (o < OFF_W1CG) {                // We1T [n][k]
                const int q = o - OFF_WE1T;
                v = We1[(size_t)(q & 255) * 128 + (q >> 8)];
            } else if (o < OFF_W1DA) {                // W1cG [l][j][w]
                const int q = o - OFF_W1CG;
                const int l = q >> 13, r = q & 8191;
                const int j = r >> 5, w = r & 31;
                v = gW1[(size_t)l * 139776 + (size_t)(512 + w) * 256 + j];
            } else if (o < OFF_W2P) {                 // W1da [l][d][j]
                const int q = o - OFF_W1DA;
                const int l = q >> 9, r = q & 511;
                v = gW1[(size_t)l * 139776 + (size_t)(544 + (r >> 8)) * 256 + (r & 255)];
            } else if (o < OFF_W2EI) {                // W2p [l][j]
                const int q = o - OFF_W2P;
                v = gW2[(size_t)(q >> 8) * 90368 + (size_t)(q & 255) * 353 + 320];
            } else if (o < OFF_WE1CG) {               // W2e fragment image [l][idx]
                const int q = o - OFF_W2EI;
                const int l = q >> 13, r = q & 8191;
                const int kk = r >> 9, lanei = (r >> 3) & 63, jj = r & 7;
                const int j = kk * 16 + (lanei >> 5) * 8 + jj;
                v = gW2[(size_t)l * 90368 + (size_t)j * 353 + 321 + (lanei & 31)];
            } else if (o < OFF_WD) {                  // We1cG [j][w]
                const int q = o - OFF_WE1CG;
                v = We1[(size_t)(256 + (q & 31)) * 128 + (q >> 5)];
            } else if (o < OFF_WE2I) {                // Wd [j]
                v = We1[288 * 128 + (o - OFF_WD)];
            } else if (o < OFF_WH2T) {                // We2 fragment image
                const int q = o - OFF_WE2I;
                const int kk = q >> 9, lanei = (q >> 3) & 63, jj = q & 7;
                const int c = lanei & 31;
                v = (c < 5) ? We2[(size_t)(kk * 16 + (lanei >> 5) * 8 + jj) * 5 + c] : 0.f;
            } else {                                  // Wh2T [n=16][k=256]
                const int q = o - OFF_WH2T;
                v = Wh2[(size_t)(q & 255) * 16 + (q >> 8)];
            }
            wb[o] = bfc(v);
        }
    } else if (b < 1280) {
        // ---- node init: h = [x|z]@Wam+bam; s, sbf, pos
        const int mol = b - 1024;
        float (*xz)[80]  = (float(*)[80])smem;
        float (*praw)[3] = (float(*)[3])(smem + 32 * 80 * 4);
        for (int idx = t; idx < 32 * 80; idx += 256) {
            const int i = idx / 80, k = idx % 80;
            xz[i][k] = (k < 16) ? x[(size_t)(mol * 32 + i) * 16 + k]
                                : z[(size_t)(mol * 32 + i) * 64 + (k - 16)];
        }
        __syncthreads();
        float acc[32];
        #pragma unroll
        for (int i = 0; i < 32; ++i) acc[i] = 0.f;
        for (int k0 = 0; k0 < 80; k0 += 4) {
            const float w0 = Wam[(k0 + 0) * 259 + t];
            const float w1 = Wam[(k0 + 1) * 259 + t];
            const float w2 = Wam[(k0 + 2) * 259 + t];
            const float w3 = Wam[(k0 + 3) * 259 + t];
            #pragma unroll
            for (int i = 0; i < 32; ++i) {
                const float4 xv = *(const float4*)&xz[i][k0];
                acc[i] += xv.x * w0 + xv.y * w1 + xv.z * w2 + xv.w * w3;
            }
        }
        const float bv = bam[t];
        #pragma unroll
        for (int i = 0; i < 32; ++i) {
            const float v = acc[i] + bv;
            s[(size_t)(mol * 32 + i) * 256 + t] = v;
            sbf[(size_t)(mol * 32 + i) * 256 + t] = bfc(v);
        }
        if (t < 96) {
            const int i = t / 3, c = t % 3;
            float a2 = bam[256 + c];
            for (int k = 0; k < 80; ++k) a2 += xz[i][k] * Wam[k * 259 + 256 + c];
            praw[i][c] = a2;
        }
        __syncthreads();
        if (t < 96) {
            const int i = t / 3, c = t % 3;
            float p = 0.f;
            for (int jj = 0; jj < 3; ++jj) p += rot[mol * 9 + c * 3 + jj] * praw[i][jj];
            pos[(size_t)(mol * 32 + i) * 3 + c] = p;
        }
    } else {
        // ---- edge init (LDS-staged ea, 1 block/mol)
        const int mol = b - 1280;
        float* sEa      = (float*)smem;
        float (*sW)[32] = (float(*)[32])(smem + 4960 * 4);
        float* sB       = (float*)(smem + (4960 + 160) * 4);
        const float* base = ea + (size_t)mol * 4960;
        for (int i = t; i < 4960; i += 256) sEa[i] = base[i];
        if (t < 160) sW[t / 32][t & 31] = Wbm[t];
        if (t < 32)  sB[t] = bbm[t];
        __syncthreads();
        for (int i = t; i < 31744; i += 256) {
            const int c = i & 31;
            const int rrn = i >> 5;
            const int n = rrn / 31, rr = rrn - n * 31;
            const int s_ = rr + (rr >= n ? 1 : 0);
            const int gl = s_ * 31 + (n - (n > s_ ? 1 : 0));
            float acc = sB[c];
            #pragma unroll
            for (int k = 0; k < 5; ++k) acc += sEa[gl * 5 + k] * sW[k][c];
            ebuf[(size_t)mol * 31744 + i] = bfc(acc);
        }
    }
}

// ---------------------------------------------------------------------------
// MFMA edge kernel with fused dual-GEMM prologue and s-update epilogue.
// Grid 512 (2/mol), 512 thr.
// XCD swizzle (r13): mol = (b&7) + 8*(b>>4), half = (b>>3)&1, so a block's
// XCD (b%8) == mol%8 == the XCD that wrote this mol's e rows (init block
// 1280+mol) and sbf/pos (init block 1024+mol). Steady layers reuse the same
// mapping -> same-XCD L2 hits for the e RMW across all dispatches.
// OCCUPANCY-ALLOCATOR LESSON (r4/r10/r11): any explicit occupancy hint
// (__launch_bounds__(N,waves) or amdgpu_waves_per_eu) makes the allocator
// pick VGPR=64 for these bodies -> ~2.7GB scratch spill, 2.2x regression.
// Only plain __launch_bounds__(512) reliably compiles at VGPR=128.
// ---------------------------------------------------------------------------
__global__ __launch_bounds__(512) void edge_mfma(
    const short* __restrict__ sbfA, const short* __restrict__ T1,
    const float* __restrict__ posIn, float* __restrict__ posOut,
    short* __restrict__ ebuf,
    const short* __restrict__ W1cG, const short* __restrict__ W1daP,
    const short* __restrict__ W2pP, const short* __restrict__ W2eimg,
    const short* __restrict__ W2sT,
    const float* __restrict__ b1, const float* __restrict__ b2,
    float* __restrict__ s, short* __restrict__ sbfOut)
{
    const int blk = blockIdx.x;
    const int mol = (blk & 7) + ((blk >> 4) << 3);
    const int nbase = ((blk >> 3) & 1) * 16;
    const int t = threadIdx.x;
    const int wave = t >> 6, lane = t & 63;
    const int l = lane & 31, half = lane >> 5;
    const int node0 = mol * 32;

    __shared__ __align__(16) short sBg[256][72];      // 36 KB
    __shared__ __align__(16) short sM[8][32][40];     // 20 KB union: phase0 = sSbf[32][264]
    __shared__ __align__(16) short sHrows[16][264];   // 8.25 KB
    __shared__ __align__(16) short sSB[16][264];      // 8.25 KB
    __shared__ float sPosS[32][4];
    __shared__ __align__(16) short sW1da[2][256];
    __shared__ __align__(16) short sW2p[256];
    __shared__ float sP[8][32];
    __shared__ float sPd[16][4];
    short* sSbf = &sM[0][0][0];   // [32][264] view, phase0 only

    // ---- phase 0a: stage W1c (pre-swizzled image), sbf block, small tables
    {
        const int j = t & 255, gh = t >> 8;
        const bf16x8 v0 = *(const bf16x8*)&W1cG[j * 32 + gh * 16];
        const bf16x8 v1 = *(const bf16x8*)&W1cG[j * 32 + gh * 16 + 8];
        const int c3 = (j >> 3) & 3;
        const int s0 = ((gh * 2 + 0) + 3 * c3) & 7;
        const int s1 = ((gh * 2 + 1) + 3 * c3) & 7;
        *(bf16x8*)&sBg[j][s0 * 8] = v0;
        *(bf16x8*)&sBg[j][s1 * 8] = v1;
    }
    {   // sbf rows -> sSbf (padded rows of 264)
        const int row = t >> 4, ch = (t & 15) * 16;
        const short* src = sbfA + (size_t)(node0 + row) * 256 + ch;
        *(bf16x8*)&sSbf[row * 264 + ch]     = *(const bf16x8*)(src);
        *(bf16x8*)&sSbf[row * 264 + ch + 8] = *(const bf16x8*)(src + 8);
    }
    if (t < 64) {
        short* d = &sW1da[0][0];
        *(bf16x8*)&d[t * 8] = *(const bf16x8*)&W1daP[t * 8];
    }
    if (t < 32) *(bf16x8*)&sW2p[t * 8] = *(const bf16x8*)&W2pP[t * 8];
    if (t < 96) sPosS[t / 3][t % 3] = posIn[node0 * 3 + t];
    __syncthreads();

    // ---- phase 0b: dual GEMM (SA -> sBg k32..63 swizzled; SB -> sSB)
    {
        const int jt = wave;                // col-tile per wave
        const int j = jt * 32 + l;
        f32x16 accA = {}, accB = {};
        #pragma unroll
        for (int k0 = 0; k0 < 256; k0 += 16) {
            const bf16x8 afr = *(const bf16x8*)&sSbf[l * 264 + k0 + half * 8];
            const bf16x8 bA  = *(const bf16x8*)(T1 + (size_t)(j) * 256 + k0 + half * 8);
            const bf16x8 bB  = *(const bf16x8*)(T1 + (size_t)(256 + j) * 256 + k0 + half * 8);
            accA = __builtin_amdgcn_mfma_f32_32x32x16_bf16(afr, bA, accA, 0,0,0);
            accB = __builtin_amdgcn_mfma_f32_32x32x16_bf16(afr, bB, accB, 0,0,0);
        }
        const int c3 = (j >> 3) & 3;
        #pragma unroll
        for (int r = 0; r < 16; ++r) {
            const int node = (r & 3) + 8 * (r >> 2) + 4 * half;
            const int k = 32 + node;
            const int slot = ((k >> 3) + 3 * c3) & 7;
            sBg[j][slot * 8 + (k & 7)] = bfc(accA[r]);
            const int nl = node - nbase;
            if ((unsigned)nl < 16u) sSB[nl][j] = bfc(accB[r]);
        }
    }
    __syncthreads();

    float b1v[8];
    short w1dv[8], w1av[8];
    #pragma unroll
    for (int cb = 0; cb < 8; ++cb) {
        b1v[cb]  = b1[cb * 32 + l];
        w1dv[cb] = sW1da[0][cb * 32 + l];
        w1av[cb] = sW1da[1][cb * 32 + l];
    }
    const float b2e = b2[321 + l];
    const float b2p = b2[320];
    int bslot[4];
    #pragma unroll
    for (int ks = 0; ks < 4; ++ks)
        bslot[ks] = ((ks * 2 + half) + 3 * ((l >> 3) & 3)) & 7;

    // prefetch ebuf fragments for BOTH ni iterations (hide latency under ni=0)
    bf16x8 efr0[2], efr1[2];
    #pragma unroll
    for (int ni = 0; ni < 2; ++ni) {
        const int n = nbase + wave + ni * 8;
        const short* ebase = ebuf + ((size_t)((mol * 32 + n) * 31 + l)) * 32;
        efr0[ni] = *(const bf16x8*)(ebase + half * 8);
        efr1[ni] = *(const bf16x8*)(ebase + 16 + half * 8);
    }

    // ---- phase 1: edge messages
    #pragma unroll
    for (int ni = 0; ni < 2; ++ni) {
        const int n = nbase + wave + ni * 8;
        const int nloc = wave + ni * 8;
        const int rrc = (l < 31) ? l : 30;
        const int src = rrc + (rrc >= n ? 1 : 0);
        const float ax = sPosS[n][0],  ay = sPosS[n][1],  az = sPosS[n][2];
        const float bx = sPosS[src][0], by = sPosS[src][1], bz = sPosS[src][2];
        const float rx = ax - bx, ry = ay - by, rz = az - bz;
        const float av = ax * bx + ay * by + az * bz;
        const float dd = sqrtf(fmaxf(rx * rx + ry * ry + rz * rz, 1e-6f));
        const float inv = __builtin_amdgcn_rcpf(1.f + dd);
        const float rnx = rx * inv, rny = ry * inv, rnz = rz * inv;

        const bf16x8 fr0 = efr0[ni];
        const bf16x8 fr1 = efr1[ni];
        bf16x8 fr2 = {}, fr3, fr4;
        if (half == 0) { fr2[0] = bfc(dd); fr2[1] = bfc(av); }
        #pragma unroll
        for (int jj = 0; jj < 8; ++jj) {
            fr3[jj] = (half * 8 + jj == src)      ? ONEBF : (short)0;
            fr4[jj] = (16 + half * 8 + jj == src) ? ONEBF : (short)0;
        }

        // opaque per-ni view of the W2e image: prevents cross-ni CSE/hoist of
        // the per-cb fragment loads back into 64 resident VGPRs.
        const short* W2ei = W2eimg;
        asm volatile("" : "+s"(W2ei));

        f32x16 accC = {}, accP = {};
        float Hacc[8];

        const int g = l >> 3, jlow = l & 7;
        #pragma unroll
        for (int cb = 0; cb < 8; ++cb) {
            // per-cb W2e fragments (L2-hot, issued before the MFMA cluster)
            const bf16x8 w2e0 = *(const bf16x8*)&W2ei[(size_t)((cb * 2 + 0) * 64 + lane) * 8];
            const bf16x8 w2e1 = *(const bf16x8*)&W2ei[(size_t)((cb * 2 + 1) * 64 + lane) * 8];
            const float sbv = bf2f(sSB[nloc][cb * 32 + l]) + b1v[cb];
            f32x16 acc;
            #pragma unroll
            for (int r = 0; r < 16; ++r) acc[r] = sbv;
            {
                const short* brow = &sBg[cb * 32 + l][0];
                __builtin_amdgcn_s_setprio(1);
                acc = __builtin_amdgcn_mfma_f32_32x32x16_bf16(fr0, *(const bf16x8*)(brow + bslot[0]*8), acc, 0,0,0);
                acc = __builtin_amdgcn_mfma_f32_32x32x16_bf16(fr1, *(const bf16x8*)(brow + bslot[1]*8), acc, 0,0,0);
                acc = __builtin_amdgcn_mfma_f32_32x32x16_bf16(fr3, *(const bf16x8*)(brow + bslot[2]*8), acc, 0,0,0);
                acc = __builtin_amdgcn_mfma_f32_32x32x16_bf16(fr4, *(const bf16x8*)(brow + bslot[3]*8), acc, 0,0,0);
                bf16x8 frB2 = {};
                if (half == 0) { frB2[0] = w1dv[cb]; frB2[1] = w1av[cb]; }
                acc = __builtin_amdgcn_mfma_f32_32x32x16_bf16(fr2, frB2, acc, 0,0,0);
                __builtin_amdgcn_s_setprio(0);
            }
            float hs = 0.f;
            #pragma unroll
            for (int r = 0; r < 16; ++r) {
                const int e = (r & 3) + 8 * (r >> 2) + 4 * half;
                float h = silu_f(acc[r]);
                if (half == 1 && r == 15) h = 0.f;   // pad row 31
                hs += h;
                sM[wave][e][((g + (e >> 3)) & 3) * 8 + jlow] = bfc(h);
            }
            Hacc[cb] = hs;
            #pragma unroll
            for (int q = 0; q < 2; ++q) {
                const bf16x8 afr  = *(const bf16x8*)&sM[wave][l][((q * 2 + half + (l >> 3)) & 3) * 8];
                const bf16x8 wpfr = *(const bf16x8*)&sW2p[cb * 32 + q * 16 + half * 8];
                accC = __builtin_amdgcn_mfma_f32_32x32x16_bf16(afr, q ? w2e1 : w2e0, accC, 0,0,0);
                accP = __builtin_amdgcn_mfma_f32_32x32x16_bf16(afr, wpfr, accP, 0,0,0);
            }
        }
        // H row into LDS tile (bf16)
        #pragma unroll
        for (int cb = 0; cb < 8; ++cb) {
            const float v = Hacc[cb] + __shfl_xor(Hacc[cb], 32, 64);
            if (lane < 32) sHrows[nloc][cb * 32 + lane] = bfc(v);
        }
        // p: accP cols all equal; lanes l==0 (both halves) scatter 16 rows each
        if (l == 0) {
            #pragma unroll
            for (int q4 = 0; q4 < 4; ++q4) {
                float4 pv = { accP[q4 * 4 + 0], accP[q4 * 4 + 1],
                              accP[q4 * 4 + 2], accP[q4 * 4 + 3] };
                *(float4*)&sP[wave][q4 * 8 + 4 * half] = pv;
            }
        }
        const float pown = sP[wave][l];
        const float pfull = (half == 0 && l < 31) ? (pown + b2p) : 0.f;
        float pd0 = rnx * pfull, pd1 = rny * pfull, pd2 = rnz * pfull;
        #pragma unroll
        for (int m = 1; m <= 32; m <<= 1) {
            pd0 += __shfl_xor(pd0, m, 64);
            pd1 += __shfl_xor(pd1, m, 64);
            pd2 += __shfl_xor(pd2, m, 64);
        }
        if (lane == 0) {
            sPd[nloc][0] = pd0;
            sPd[nloc][1] = pd1;
            sPd[nloc][2] = pd2;
        }
        // e update (bf16 RMW)
        #pragma unroll
        for (int r = 0; r < 16; ++r) {
            const int e = (r & 3) + 8 * (r >> 2) + 4 * half;
            if (e < 31) {
                short* ep = ebuf + ((size_t)((mol * 32 + n) * 31 + e)) * 32 + l;
                *ep = bfc(bf2f(*ep) + accC[r] + b2e);
            }
        }
    }

    __syncthreads();  // H-tile + sPd complete

    // ---- phase 2: s-update via 16x16x32 MFMA (16 rows, no padding)
    {
        const int jb0 = wave * 32;
        const int arow = lane & 15, kg = lane >> 4;   // kg in 0..3
        f32x4 accS0 = {}, accS1 = {};
        #pragma unroll
        for (int k0 = 0; k0 < 256; k0 += 32) {
            const bf16x8 afr = *(const bf16x8*)&sHrows[arow][k0 + kg * 8];
            const bf16x8 bf0 = *(const bf16x8*)&W2sT[(size_t)(jb0 + arow) * 256 + k0 + kg * 8];
            const bf16x8 bf1 = *(const bf16x8*)&W2sT[(size_t)(jb0 + 16 + arow) * 256 + k0 + kg * 8];
            accS0 = __builtin_amdgcn_mfma_f32_16x16x32_bf16(afr, bf0, accS0, 0,0,0);
            accS1 = __builtin_amdgcn_mfma_f32_16x16x32_bf16(afr, bf1, accS1, 0,0,0);
        }
        const int col = lane & 15;
        const int orow = (lane >> 4) * 4;
        const float bv0 = b2[jb0 + col];
        const float bv1 = b2[jb0 + 16 + col];
        #pragma unroll
        for (int r = 0; r < 4; ++r) {
            const int node = node0 + nbase + orow + r;
            {
                float* sp = s + (size_t)node * 256 + jb0 + col;
                const float nv = *sp + accS0[r] * (1.f / 31.f) + bv0;
                *sp = nv;
                sbfOut[(size_t)node * 256 + jb0 + col] = bfc(nv);
            }
            {
                float* sp = s + (size_t)node * 256 + jb0 + 16 + col;
                const float nv = *sp + accS1[r] * (1.f / 31.f) + bv1;
                *sp = nv;
                sbfOut[(size_t)node * 256 + jb0 + 16 + col] = bfc(nv);
            }
        }
    }
    // pos update
    if (t < 48) {
        const int nl = t / 3, c = t % 3;
        const int node = node0 + nbase + nl;
        posOut[(size_t)node * 3 + c] = posIn[(size_t)node * 3 + c] + sPd[nl][c] * (1.f / 31.f);
    }
}

// ---------------------------------------------------------------------------
// MFMA bond kernel: fused U-GEMM prologue, atoms epilogue (silu(s@Wh1)@Wh2),
// and pos output copy. Grid 512, 512 thr. Same XCD swizzle as edge_mfma so
// its e reads hit the L2 lines written by layer-4's same-XCD blocks.
// ---------------------------------------------------------------------------
__global__ __launch_bounds__(512) void bond_mfma(
    const short* __restrict__ sbfA, const short* __restrict__ We1T,
    const float* __restrict__ pos, short* __restrict__ ebuf,
    const short* __restrict__ We1cG, const short* __restrict__ WdP,
    const short* __restrict__ We2img, const short* __restrict__ Wh1T,
    const short* __restrict__ Wh2I,
    const float* __restrict__ be1, const float* __restrict__ be2,
    const float* __restrict__ bh1, const float* __restrict__ bh2,
    float* __restrict__ outA, float* __restrict__ outB,
    float* __restrict__ outPos)
{
    const int blk = blockIdx.x;
    const int mol = (blk & 7) + ((blk >> 4) << 3);
    const int nbase = ((blk >> 3) & 1) * 16;
    const int t = threadIdx.x;
    const int wave = t >> 6, lane = t & 63;
    const int l = lane & 31, half = lane >> 5;
    const int node0 = mol * 32;

    __shared__ __align__(16) short sBg2[128][72];
    __shared__ __align__(16) short sHdnB[8][32][40];
    __shared__ __align__(16) short sU[32][136];
    __shared__ float sPosS[32][4];
    __shared__ __align__(16) short sWd[128];
    short* sSbf = &sHdnB[0][0][0];   // [32][264] view, phase0 only

    {
        const int j = t & 127, g = t >> 7;
        const bf16x8 v = *(const bf16x8*)&We1cG[j * 32 + g * 8];
        const int slot = (g + 3 * ((j >> 3) & 3)) & 7;
        *(bf16x8*)&sBg2[j][slot * 8] = v;
    }
    {
        const int row = t >> 4, ch = (t & 15) * 16;
        const short* src = sbfA + (size_t)(node0 + row) * 256 + ch;
        *(bf16x8*)&sSbf[row * 264 + ch]     = *(const bf16x8*)(src);
        *(bf16x8*)&sSbf[row * 264 + ch + 8] = *(const bf16x8*)(src + 8);
    }
    if (t < 16) *(bf16x8*)&sWd[t * 8] = *(const bf16x8*)&WdP[t * 8];
    if (t < 96) sPosS[t / 3][t % 3] = pos[node0 * 3 + t];
    __syncthreads();

    if (wave < 4) {
        const int j = wave * 32 + l;
        f32x16 accU = {};
        #pragma unroll
        for (int k0 = 0; k0 < 256; k0 += 16) {
            const bf16x8 afr = *(const bf16x8*)&sSbf[l * 264 + k0 + half * 8];
            const bf16x8 bU  = *(const bf16x8*)(We1T + (size_t)j * 256 + k0 + half * 8);
            accU = __builtin_amdgcn_mfma_f32_32x32x16_bf16(afr, bU, accU, 0,0,0);
        }
        const int c3 = (j >> 3) & 3;
        #pragma unroll
        for (int r = 0; r < 16; ++r) {
            const int node = (r & 3) + 8 * (r >> 2) + 4 * half;
            const short uv = bfc(accU[r]);
            const int k = 32 + node;
            const int slot = ((k >> 3) + 3 * c3) & 7;
            sBg2[j][slot * 8 + (k & 7)] = uv;
            sU[node][j] = uv;
        }
    }

    float be1v[4];
    #pragma unroll
    for (int cb = 0; cb < 4; ++cb) be1v[cb] = be1[cb * 32 + l];
    const float be2v = (l < 5) ? be2[l] : 0.f;
    int bslot[4];
    #pragma unroll
    for (int ks = 0; ks < 4; ++ks)
        bslot[ks] = ((ks * 2 + half) + 3 * ((l >> 3) & 3)) & 7;
    __syncthreads();

    bf16x8 efr0[2], efr1[2];
    #pragma unroll
    for (int ni = 0; ni < 2; ++ni) {
        const int n = nbase + wave + ni * 8;
        const short* ebase = ebuf + ((size_t)((mol * 32 + n) * 31 + l)) * 32;
        efr0[ni] = *(const bf16x8*)(ebase + half * 8);
        efr1[ni] = *(const bf16x8*)(ebase + 16 + half * 8);
    }

    #pragma unroll
    for (int ni = 0; ni < 2; ++ni) {
        const int n = nbase + wave + ni * 8;
        const int rrc = (l < 31) ? l : 30;
        const int src = rrc + (rrc >= n ? 1 : 0);
        const float rx = sPosS[n][0] - sPosS[src][0];
        const float ry = sPosS[n][1] - sPosS[src][1];
        const float rz = sPosS[n][2] - sPosS[src][2];
        const float dd = sqrtf(fmaxf(rx * rx + ry * ry + rz * rz, 1e-6f));

        const bf16x8 fr0 = efr0[ni];
        const bf16x8 fr1 = efr1[ni];
        bf16x8 fr2 = {}, fr3, fr4;
        if (half == 0) fr2[0] = bfc(dd);
        #pragma unroll
        for (int jj = 0; jj < 8; ++jj) {
            fr3[jj] = (half * 8 + jj == src)      ? ONEBF : (short)0;
            fr4[jj] = (16 + half * 8 + jj == src) ? ONEBF : (short)0;
        }

        const short* We2i = We2img;
        asm volatile("" : "+s"(We2i));

        f32x16 accC = {};
        const int g = l >> 3, jlow = l & 7;
        #pragma unroll
        for (int cb = 0; cb < 4; ++cb) {
            const bf16x8 w2f0 = *(const bf16x8*)&We2i[(size_t)((cb * 2 + 0) * 64 + lane) * 8];
            const bf16x8 w2f1 = *(const bf16x8*)&We2i[(size_t)((cb * 2 + 1) * 64 + lane) * 8];
            const float uin = bf2f(sU[n][cb * 32 + l]) + be1v[cb];
            f32x16 acc;
            #pragma unroll
            for (int r = 0; r < 16; ++r) acc[r] = uin;
            {
                const short* brow = &sBg2[cb * 32 + l][0];
                acc = __builtin_amdgcn_mfma_f32_32x32x16_bf16(fr0, *(const bf16x8*)(brow + bslot[0]*8), acc, 0,0,0);
                acc = __builtin_amdgcn_mfma_f32_32x32x16_bf16(fr1, *(const bf16x8*)(brow + bslot[1]*8), acc, 0,0,0);
                acc = __builtin_amdgcn_mfma_f32_32x32x16_bf16(fr3, *(const bf16x8*)(brow + bslot[2]*8), acc, 0,0,0);
                acc = __builtin_amdgcn_mfma_f32_32x32x16_bf16(fr4, *(const bf16x8*)(brow + bslot[3]*8), acc, 0,0,0);
                bf16x8 frWd = {};
                if (half == 0) frWd[0] = sWd[cb * 32 + l];
                acc = __builtin_amdgcn_mfma_f32_32x32x16_bf16(fr2, frWd, acc, 0,0,0);
            }
            #pragma unroll
            for (int r = 0; r < 16; ++r) {
                const int e = (r & 3) + 8 * (r >> 2) + 4 * half;
                sHdnB[wave][e][((g + (e >> 3)) & 3) * 8 + jlow] = bfc(silu_f(acc[r]));
            }
            #pragma unroll
            for (int q = 0; q < 2; ++q) {
                const bf16x8 afr = *(const bf16x8*)&sHdnB[wave][l][((q * 2 + half + (l >> 3)) & 3) * 8];
                accC = __builtin_amdgcn_mfma_f32_32x32x16_bf16(afr, q ? w2f1 : w2f0, accC, 0,0,0);
            }
        }
        if (l < 5) {
            #pragma unroll
            for (int r = 0; r < 16; ++r) {
                const int e = (r & 3) + 8 * (r >> 2) + 4 * half;
                if (e < 31) {
                    const int s_ = e + (e >= n ? 1 : 0);
                    const int ge = (mol * 32 + s_) * 31 + (n - (n > s_ ? 1 : 0));
                    outB[(size_t)ge * 5 + l] = accC[r] + be2v;
                }
            }
        }
    }
    if (t < 48) {
        const int nl = t / 3, c = t % 3;
        const int node = node0 + nbase + nl;
        outPos[(size_t)node * 3 + c] = pos[(size_t)node * 3 + c];
    }

    // ---- phase 3: atoms
    __syncthreads();
    {
        short* sA3 = &sU[0][0];
        const int row = t >> 5, ch = (t & 31) * 8;
        *(bf16x8*)&sA3[row * 264 + ch] =
            *(const bf16x8*)(sbfA + (size_t)(node0 + nbase + row) * 256 + ch);
    }
    __syncthreads();
    {
        short* sA3 = &sU[0][0];
        short* sT  = &sBg2[0][0];
        const int jb0 = wave * 32;
        const int arow = lane & 15, kg = lane >> 4;
        f32x4 a0 = {}, a1 = {};
        #pragma unroll
        for (int k0 = 0; k0 < 256; k0 += 32) {
            const bf16x8 afr = *(const bf16x8*)&sA3[arow * 264 + k0 + kg * 8];
            const bf16x8 bw0 = *(const bf16x8*)(Wh1T + (size_t)(jb0 + arow) * 256 + k0 + kg * 8);
            const bf16x8 bw1 = *(const bf16x8*)(Wh1T + (size_t)(jb0 + 16 + arow) * 256 + k0 + kg * 8);
            a0 = __builtin_amdgcn_mfma_f32_16x16x32_bf16(afr, bw0, a0, 0,0,0);
            a1 = __builtin_amdgcn_mfma_f32_16x16x32_bf16(afr, bw1, a1, 0,0,0);
        }
        const int col = lane & 15, orow = (lane >> 4) * 4;
        const float bva = bh1[jb0 + col], bvb = bh1[jb0 + 16 + col];
        #pragma unroll
        for (int r = 0; r < 4; ++r) {
            sT[(orow + r) * 264 + jb0 + col]      = bfc(silu_f(a0[r] + bva));
            sT[(orow + r) * 264 + jb0 + 16 + col] = bfc(silu_f(a1[r] + bvb));
        }
    }
    __syncthreads();
    if (wave == 0) {
        short* sT = &sBg2[0][0];
        const int arow = lane & 15, kg = lane >> 4;
        f32x4 a2 = {};
        #pragma unroll
        for (int k0 = 0; k0 < 256; k0 += 32) {
            const bf16x8 afr = *(const bf16x8*)&sT[arow * 264 + k0 + kg * 8];
            const bf16x8 bfr = *(const bf16x8*)(Wh2I + (size_t)arow * 256 + k0 + kg * 8);
            a2 = __builtin_amdgcn_mfma_f32_16x16x32_bf16(afr, bfr, a2, 0,0,0);
        }
        const int col = lane & 15, orow = (lane >> 4) * 4;
        const float bv = bh2[col];
        #pragma unroll
        for (int r = 0; r < 4; ++r)
            outA[(size_t)(node0 + nbase + orow + r) * 16 + col] = a2[r] + bv;
    }
}

// ---------------------------------------------------------------------------
extern "C" void kernel_launch(void* const* d_in, const int* in_sizes, int n_in,
                              void* d_out, int out_size, void* d_ws, size_t ws_size,
                              hipStream_t stream) {
    const float* x   = (const float*)d_in[0];
    const float* z   = (const float*)d_in[1];
    const float* rot = (const float*)d_in[2];
    const float* ea  = (const float*)d_in[4];
    const float* Wam = (const float*)d_in[6];
    const float* bam = (const float*)d_in[7];
    const float* Wbm = (const float*)d_in[8];
    const float* bbm = (const float*)d_in[9];
    const float* gW1 = (const float*)d_in[10];
    const float* gb1 = (const float*)d_in[11];
    const float* gW2 = (const float*)d_in[12];
    const float* gb2 = (const float*)d_in[13];
    const float* Wh1 = (const float*)d_in[14];
    const float* bh1 = (const float*)d_in[15];
    const float* Wh2 = (const float*)d_in[16];
    const float* bh2 = (const float*)d_in[17];
    const float* We1 = (const float*)d_in[18];
    const float* be1 = (const float*)d_in[19];
    const float* We2 = (const float*)d_in[20];
    const float* be2 = (const float*)d_in[21];
    float* out = (float*)d_out;

    float* ws  = (float*)d_ws;
    float* s    = ws;                       // 8192*256 fp32
    float* pos  = ws + 2097152;             // 8192*3 (ping)
    short* e    = (short*)(ws + 2121728);   // 8192*31*32 bf16
    short* wb   = (short*)(ws + 6184960);   // weight images
    short* sbf0 = (short*)(ws + 6774784);   // 8192*256 bf16 (ping)
    short* sbf1 = (short*)(ws + 10248192);  // 8192*256 bf16 (pong)
    float* pos2 = ws + 16539648;            // 8192*3 (pong)

    init_all<<<1536, 256, 0, stream>>>(x, z, rot, Wam, bam, ea, Wbm, bbm,
        gW1, gW2, Wh1, We1, We2, Wh2, s, sbf0, pos, e, wb);

    float* pbuf[2] = { pos, pos2 };
    short* sbb[2] = { sbf0, sbf1 };
    for (int l = 0; l < LAYERS_; ++l) {
        const float* b1 = gb1 + l * 256;
        const float* b2 = gb2 + l * 353;
        edge_mfma<<<2 * N_MOLS, 512, 0, stream>>>(
            sbb[l & 1], wb + OFF_T1 + (size_t)l * 131072,
            pbuf[l & 1], pbuf[(l + 1) & 1], e,
            wb + OFF_W1CG + l * 8192, wb + OFF_W1DA + l * 512,
            wb + OFF_W2P + l * 256, wb + OFF_W2EI + l * 8192,
            wb + OFF_W2ST + (size_t)l * 65536,
            b1, b2, s, sbb[(l + 1) & 1]);
    }
    float* posF = pbuf[LAYERS_ & 1];
    short* sbfF = sbb[LAYERS_ & 1];

    bond_mfma<<<2 * N_MOLS, 512, 0, stream>>>(
        sbfF, wb + OFF_WE1T, posF, e, wb + OFF_WE1CG, wb + OFF_WD,
        wb + OFF_WE2I, wb + OFF_WH1T, wb + OFF_WH2T,
        be1, be2, bh1, bh2, out, out + 131072, out + 131072 + 1269760);
}

// Round 14
// 567.871 us; speedup vs baseline: 2.2942x; 1.0184x over previous
//
#include <hip/hip_runtime.h>
#include <hip/hip_bf16.h>
#include <cstdint>
#include <cstddef>

#define N_MOLS 256
#define NN     8192
#define SDIM_  256
#define NAF_   16
#define LAYERS_ 5

typedef __attribute__((ext_vector_type(8)))  short bf16x8;
typedef __attribute__((ext_vector_type(16))) float f32x16;
typedef __attribute__((ext_vector_type(4)))  float f32x4;

// fast silu: v_rcp instead of IEEE divide (~13 -> ~5 VALU ops; rounded to bf16
// downstream so the 1-ulp rcp error is invisible).
__device__ __forceinline__ float silu_f(float x) {
    return x * __builtin_amdgcn_rcpf(1.f + __expf(-x));
}
__device__ __forceinline__ short bfc(float f) {
    __hip_bfloat16 h = __float2bfloat16(f);
    return __builtin_bit_cast(short, h);
}
__device__ __forceinline__ float bf2f(short h) {
    union { uint32_t u; float f; } v; v.u = ((uint32_t)(unsigned short)h) << 16; return v.f;
}
#define ONEBF ((short)0x3F80)

// ---------------------------------------------------------------------------
// weight image offsets (in shorts, within wb)
// ---------------------------------------------------------------------------
#define OFF_T1    0         // 5 * 512*256   : W1ab^T  [l][j2][k]
#define OFF_W2ST  655360    // 5 * 256*256   : W2s^T   [l][n][k]
#define OFF_WH1T  983040    // 256*256       : Wh1^T   [n][k]
#define OFF_WE1T  1048576   // 128*256       : We1^T   [n][k]
#define OFF_W1CG  1081344   // 5 * 256*32    : W1c slot groups [l][j][w]
#define OFF_W1DA  1122304   // 5 * 2*256    : W1 d/a rows
#define OFF_W2P   1124864   // 5 * 256       : W2 col 320
#define OFF_W2EI  1126144   // 5 * 8192      : sW2e fragment image
#define OFF_WE1CG 1167104   // 128*32        : We1c slot groups
#define OFF_WD    1171200   // 128           : We1 row 288
#define OFF_WE2I  1171328   // 8*64*8        : We2 fragment image
#define OFF_WH2T  1175424   // 16*256        : Wh2^T [n=16][k=256]
#define W_TOTAL   1179520

// ---------------------------------------------------------------------------
// merged init (r14 grid = 840):
//   [0,264)    : 64x64 LDS-tiled transposes (T1 160, W2sT 80, Wh1T 16, We1T 8)
//                -- replaces column-strided scalar reads (~16x overfetch)
//   [264,328)  : scalar path for the small swizzled images (W1CG..WH2T)
//   [328,584)  : node init (1 block/mol)
//   [584,840)  : edge init (1 block/mol)
// ---------------------------------------------------------------------------
__global__ __launch_bounds__(256) void init_all(
    const float* __restrict__ x, const float* __restrict__ z,
    const float* __restrict__ rot, const float* __restrict__ Wam,
    const float* __restrict__ bam, const float* __restrict__ ea,
    const float* __restrict__ Wbm, const float* __restrict__ bbm,
    const float* __restrict__ gW1, const float* __restrict__ gW2,
    const float* __restrict__ Wh1, const float* __restrict__ We1,
    const float* __restrict__ We2, const float* __restrict__ Wh2,
    float* __restrict__ s, short* __restrict__ sbf, float* __restrict__ pos,
    short* __restrict__ ebuf, short* __restrict__ wb)
{
    __shared__ __align__(16) char smem[20608];
    const int b = blockIdx.x, t = threadIdx.x;
    if (b < 264) {
        // ---- tiled transposes: dst[n][k] = src[k][n], 64x64 tiles
        float (*lds)[65] = (float(*)[65])smem;
        const float* src; short* dst;
        int srs, tile, tr, tc;
        if (b < 160) {              // T1: 5 layers x 2 halves x 16 tiles
            const int l = b >> 5, h = (b >> 4) & 1;
            tile = b & 15;
            src = gW1 + (size_t)l * 139776 + h * 65536;   // [k][c], row len 256
            dst = wb + OFF_T1 + (size_t)l * 131072 + h * 65536;
            srs = 256; tr = tile >> 2; tc = tile & 3;
        } else if (b < 240) {       // W2sT: 5 layers x 16 tiles
            const int l = (b - 160) >> 4;
            tile = (b - 160) & 15;
            src = gW2 + (size_t)l * 90368;                // [k][n], row len 353
            dst = wb + OFF_W2ST + (size_t)l * 65536;
            srs = 353; tr = tile >> 2; tc = tile & 3;
        } else if (b < 256) {       // Wh1T: 16 tiles
            tile = b - 240;
            src = Wh1; dst = wb + OFF_WH1T;
            srs = 256; tr = tile >> 2; tc = tile & 3;
        } else {                    // We1T: 4 k-tiles x 2 n-tiles
            tile = b - 256;
            src = We1; dst = wb + OFF_WE1T;
            srs = 128; tr = tile >> 1; tc = tile & 1;
        }
        #pragma unroll 4
        for (int rep = 0; rep < 16; ++rep) {
            const int i = rep * 4 + (t >> 6), j = t & 63;
            lds[i][j] = src[(size_t)(tr * 64 + i) * srs + tc * 64 + j];
        }
        __syncthreads();
        #pragma unroll 4
        for (int rep = 0; rep < 16; ++rep) {
            const int j = rep * 4 + (t >> 6), i = t & 63;
            dst[(size_t)(tc * 64 + j) * 256 + tr * 64 + i] = bfc(lds[i][j]);
        }
    } else if (b < 328) {
        // ---- scalar path for small swizzled images
        for (int o = OFF_W1CG + (b - 264) * 256 + t; o < W_TOTAL; o += 64 * 256) {
            float v;
            if (o < OFF_W1DA) {                       // W1cG [l][j][w]
                const int q = o - OFF_W1CG;
                const int l = q >> 13, r = q & 8191;
                const int j = r >> 5, w = r & 31;
                v = gW1[(size_t)l * 139776 + (size_t)(512 + w) * 256 + j];
            } else if (o < OFF_W2P) {                 // W1da [l][d][j]
                const int q = o - OFF_W1DA;
                const int l = q >> 9, r = q & 511;
                v = gW1[(size_t)l * 139776 + (size_t)(544 + (r >> 8)) * 256 + (r & 255)];
            } else if (o < OFF_W2EI) {                // W2p [l][j]
                const int q = o - OFF_W2P;
                v = gW2[(size_t)(q >> 8) * 90368 + (size_t)(q & 255) * 353 + 320];
            } else if (o < OFF_WE1CG) {               // W2e fragment image [l][idx]
                const int q = o - OFF_W2EI;
                const int l = q >> 13, r = q & 8191;
                const int kk = r >> 9, lanei = (r >> 3) & 63, jj = r & 7;
                const int j = kk * 16 + (lanei >> 5) * 8 + jj;
                v = gW2[(size_t)l * 90368 + (size_t)j * 353 + 321 + (lanei & 31)];
            } else if (o < OFF_WD) {                  // We1cG [j][w]
                const int q = o - OFF_WE1CG;
                v = We1[(size_t)(256 + (q & 31)) * 128 + (q >> 5)];
            } else if (o < OFF_WE2I) {                // Wd [j]
                v = We1[288 * 128 + (o - OFF_WD)];
            } else if (o < OFF_WH2T) {                // We2 fragment image
                const int q = o - OFF_WE2I;
                const int kk = q >> 9, lanei = (q >> 3) & 63, jj = q & 7;
                const int c = lanei & 31;
                v = (c < 5) ? We2[(size_t)(kk * 16 + (lanei >> 5) * 8 + jj) * 5 + c] : 0.f;
            } else {                                  // Wh2T [n=16][k=256]
                const int q = o - OFF_WH2T;
                v = Wh2[(size_t)(q & 255) * 16 + (q >> 8)];
            }
            wb[o] = bfc(v);
        }
    } else if (b < 584) {
        // ---- node init: h = [x|z]@Wam+bam; s, sbf, pos
        const int mol = b - 328;
        float (*xz)[80]  = (float(*)[80])smem;
        float (*praw)[3] = (float(*)[3])(smem + 32 * 80 * 4);
        for (int idx = t; idx < 32 * 80; idx += 256) {
            const int i = idx / 80, k = idx % 80;
            xz[i][k] = (k < 16) ? x[(size_t)(mol * 32 + i) * 16 + k]
                                : z[(size_t)(mol * 32 + i) * 64 + (k - 16)];
        }
        __syncthreads();
        float acc[32];
        #pragma unroll
        for (int i = 0; i < 32; ++i) acc[i] = 0.f;
        for (int k0 = 0; k0 < 80; k0 += 4) {
            const float w0 = Wam[(k0 + 0) * 259 + t];
            const float w1 = Wam[(k0 + 1) * 259 + t];
            const float w2 = Wam[(k0 + 2) * 259 + t];
            const float w3 = Wam[(k0 + 3) * 259 + t];
            #pragma unroll
            for (int i = 0; i < 32; ++i) {
                const float4 xv = *(const float4*)&xz[i][k0];
                acc[i] += xv.x * w0 + xv.y * w1 + xv.z * w2 + xv.w * w3;
            }
        }
        const float bv = bam[t];
        #pragma unroll
        for (int i = 0; i < 32; ++i) {
            const float v = acc[i] + bv;
            s[(size_t)(mol * 32 + i) * 256 + t] = v;
            sbf[(size_t)(mol * 32 + i) * 256 + t] = bfc(v);
        }
        if (t < 96) {
            const int i = t / 3, c = t % 3;
            float a2 = bam[256 + c];
            for (int k = 0; k < 80; ++k) a2 += xz[i][k] * Wam[k * 259 + 256 + c];
            praw[i][c] = a2;
        }
        __syncthreads();
        if (t < 96) {
            const int i = t / 3, c = t % 3;
            float p = 0.f;
            for (int jj = 0; jj < 3; ++jj) p += rot[mol * 9 + c * 3 + jj] * praw[i][jj];
            pos[(size_t)(mol * 32 + i) * 3 + c] = p;
        }
    } else {
        // ---- edge init (LDS-staged ea, 1 block/mol)
        const int mol = b - 584;
        float* sEa      = (float*)smem;
        float (*sW)[32] = (float(*)[32])(smem + 4960 * 4);
        float* sB       = (float*)(smem + (4960 + 160) * 4);
        const float* base = ea + (size_t)mol * 4960;
        for (int i = t; i < 4960; i += 256) sEa[i] = base[i];
        if (t < 160) sW[t / 32][t & 31] = Wbm[t];
        if (t < 32)  sB[t] = bbm[t];
        __syncthreads();
        for (int i = t; i < 31744; i += 256) {
            const int c = i & 31;
            const int rrn = i >> 5;
            const int n = rrn / 31, rr = rrn - n * 31;
            const int s_ = rr + (rr >= n ? 1 : 0);
            const int gl = s_ * 31 + (n - (n > s_ ? 1 : 0));
            float acc = sB[c];
            #pragma unroll
            for (int k = 0; k < 5; ++k) acc += sEa[gl * 5 + k] * sW[k][c];
            ebuf[(size_t)mol * 31744 + i] = bfc(acc);
        }
    }
}

// ---------------------------------------------------------------------------
// MFMA edge kernel with fused dual-GEMM prologue and s-update epilogue.
// Grid 512 (2/mol), 512 thr.
// XCD swizzle: mol = (b&7) + 8*(b>>4), half = (b>>3)&1 (same-XCD e reuse).
// OCCUPANCY-ALLOCATOR LESSON (r4/r10/r11): any explicit occupancy hint
// makes the allocator pick VGPR=64 -> ~2.7GB scratch spill. Only plain
// __launch_bounds__(512) reliably compiles at VGPR=128.
// ---------------------------------------------------------------------------
__global__ __launch_bounds__(512) void edge_mfma(
    const short* __restrict__ sbfA, const short* __restrict__ T1,
    const float* __restrict__ posIn, float* __restrict__ posOut,
    short* __restrict__ ebuf,
    const short* __restrict__ W1cG, const short* __restrict__ W1daP,
    const short* __restrict__ W2pP, const short* __restrict__ W2eimg,
    const short* __restrict__ W2sT,
    const float* __restrict__ b1, const float* __restrict__ b2,
    float* __restrict__ s, short* __restrict__ sbfOut)
{
    const int blk = blockIdx.x;
    const int mol = (blk & 7) + ((blk >> 4) << 3);
    const int nbase = ((blk >> 3) & 1) * 16;
    const int t = threadIdx.x;
    const int wave = t >> 6, lane = t & 63;
    const int l = lane & 31, half = lane >> 5;
    const int node0 = mol * 32;

    __shared__ __align__(16) short sBg[256][72];      // 36 KB
    __shared__ __align__(16) short sM[8][32][40];     // 20 KB union: phase0 = sSbf[32][264]
    __shared__ __align__(16) short sHrows[16][264];   // 8.25 KB
    __shared__ __align__(16) short sSB[16][264];      // 8.25 KB
    __shared__ float sPosS[32][4];
    __shared__ __align__(16) short sW1da[2][256];
    __shared__ __align__(16) short sW2p[256];
    __shared__ float sP[8][32];
    __shared__ float sPd[16][4];
    short* sSbf = &sM[0][0][0];   // [32][264] view, phase0 only

    // ---- phase 0a: stage W1c (pre-swizzled image), sbf block, small tables
    {
        const int j = t & 255, gh = t >> 8;
        const bf16x8 v0 = *(const bf16x8*)&W1cG[j * 32 + gh * 16];
        const bf16x8 v1 = *(const bf16x8*)&W1cG[j * 32 + gh * 16 + 8];
        const int c3 = (j >> 3) & 3;
        const int s0 = ((gh * 2 + 0) + 3 * c3) & 7;
        const int s1 = ((gh * 2 + 1) + 3 * c3) & 7;
        *(bf16x8*)&sBg[j][s0 * 8] = v0;
        *(bf16x8*)&sBg[j][s1 * 8] = v1;
    }
    {   // sbf rows -> sSbf (padded rows of 264)
        const int row = t >> 4, ch = (t & 15) * 16;
        const short* src = sbfA + (size_t)(node0 + row) * 256 + ch;
        *(bf16x8*)&sSbf[row * 264 + ch]     = *(const bf16x8*)(src);
        *(bf16x8*)&sSbf[row * 264 + ch + 8] = *(const bf16x8*)(src + 8);
    }
    if (t < 64) {
        short* d = &sW1da[0][0];
        *(bf16x8*)&d[t * 8] = *(const bf16x8*)&W1daP[t * 8];
    }
    if (t < 32) *(bf16x8*)&sW2p[t * 8] = *(const bf16x8*)&W2pP[t * 8];
    if (t < 96) sPosS[t / 3][t % 3] = posIn[node0 * 3 + t];
    __syncthreads();

    // ---- phase 0b: dual GEMM (SA -> sBg k32..63 swizzled; SB -> sSB)
    {
        const int jt = wave;                // col-tile per wave
        const int j = jt * 32 + l;
        f32x16 accA = {}, accB = {};
        #pragma unroll
        for (int k0 = 0; k0 < 256; k0 += 16) {
            const bf16x8 afr = *(const bf16x8*)&sSbf[l * 264 + k0 + half * 8];
            const bf16x8 bA  = *(const bf16x8*)(T1 + (size_t)(j) * 256 + k0 + half * 8);
            const bf16x8 bB  = *(const bf16x8*)(T1 + (size_t)(256 + j) * 256 + k0 + half * 8);
            accA = __builtin_amdgcn_mfma_f32_32x32x16_bf16(afr, bA, accA, 0,0,0);
            accB = __builtin_amdgcn_mfma_f32_32x32x16_bf16(afr, bB, accB, 0,0,0);
        }
        const int c3 = (j >> 3) & 3;
        #pragma unroll
        for (int r = 0; r < 16; ++r) {
            const int node = (r & 3) + 8 * (r >> 2) + 4 * half;
            const int k = 32 + node;
            const int slot = ((k >> 3) + 3 * c3) & 7;
            sBg[j][slot * 8 + (k & 7)] = bfc(accA[r]);
            const int nl = node - nbase;
            if ((unsigned)nl < 16u) sSB[nl][j] = bfc(accB[r]);
        }
    }
    __syncthreads();

    float b1v[8];
    short w1dv[8], w1av[8];
    #pragma unroll
    for (int cb = 0; cb < 8; ++cb) {
        b1v[cb]  = b1[cb * 32 + l];
        w1dv[cb] = sW1da[0][cb * 32 + l];
        w1av[cb] = sW1da[1][cb * 32 + l];
    }
    const float b2e = b2[321 + l];
    const float b2p = b2[320];
    int bslot[4];
    #pragma unroll
    for (int ks = 0; ks < 4; ++ks)
        bslot[ks] = ((ks * 2 + half) + 3 * ((l >> 3) & 3)) & 7;

    // prefetch ebuf fragments for BOTH ni iterations (hide latency under ni=0)
    bf16x8 efr0[2], efr1[2];
    #pragma unroll
    for (int ni = 0; ni < 2; ++ni) {
        const int n = nbase + wave + ni * 8;
        const short* ebase = ebuf + ((size_t)((mol * 32 + n) * 31 + l)) * 32;
        efr0[ni] = *(const bf16x8*)(ebase + half * 8);
        efr1[ni] = *(const bf16x8*)(ebase + 16 + half * 8);
    }

    // ---- phase 1: edge messages
    #pragma unroll
    for (int ni = 0; ni < 2; ++ni) {
        const int n = nbase + wave + ni * 8;
        const int nloc = wave + ni * 8;
        const int rrc = (l < 31) ? l : 30;
        const int src = rrc + (rrc >= n ? 1 : 0);
        const float ax = sPosS[n][0],  ay = sPosS[n][1],  az = sPosS[n][2];
        const float bx = sPosS[src][0], by = sPosS[src][1], bz = sPosS[src][2];
        const float rx = ax - bx, ry = ay - by, rz = az - bz;
        const float av = ax * bx + ay * by + az * bz;
        const float dd = sqrtf(fmaxf(rx * rx + ry * ry + rz * rz, 1e-6f));
        const float inv = __builtin_amdgcn_rcpf(1.f + dd);
        const float rnx = rx * inv, rny = ry * inv, rnz = rz * inv;

        const bf16x8 fr0 = efr0[ni];
        const bf16x8 fr1 = efr1[ni];
        bf16x8 fr2 = {}, fr3, fr4;
        if (half == 0) { fr2[0] = bfc(dd); fr2[1] = bfc(av); }
        #pragma unroll
        for (int jj = 0; jj < 8; ++jj) {
            fr3[jj] = (half * 8 + jj == src)      ? ONEBF : (short)0;
            fr4[jj] = (16 + half * 8 + jj == src) ? ONEBF : (short)0;
        }

        // opaque per-ni view of the W2e image: prevents cross-ni CSE/hoist of
        // the per-cb fragment loads back into 64 resident VGPRs.
        const short* W2ei = W2eimg;
        asm volatile("" : "+s"(W2ei));

        f32x16 accC = {}, accP = {};
        float Hacc[8];

        const int g = l >> 3, jlow = l & 7;
        #pragma unroll
        for (int cb = 0; cb < 8; ++cb) {
            // per-cb W2e fragments (L2-hot, issued before the MFMA cluster)
            const bf16x8 w2e0 = *(const bf16x8*)&W2ei[(size_t)((cb * 2 + 0) * 64 + lane) * 8];
            const bf16x8 w2e1 = *(const bf16x8*)&W2ei[(size_t)((cb * 2 + 1) * 64 + lane) * 8];
            const float sbv = bf2f(sSB[nloc][cb * 32 + l]) + b1v[cb];
            f32x16 acc;
            #pragma unroll
            for (int r = 0; r < 16; ++r) acc[r] = sbv;
            {
                const short* brow = &sBg[cb * 32 + l][0];
                __builtin_amdgcn_s_setprio(1);
                acc = __builtin_amdgcn_mfma_f32_32x32x16_bf16(fr0, *(const bf16x8*)(brow + bslot[0]*8), acc, 0,0,0);
                acc = __builtin_amdgcn_mfma_f32_32x32x16_bf16(fr1, *(const bf16x8*)(brow + bslot[1]*8), acc, 0,0,0);
                acc = __builtin_amdgcn_mfma_f32_32x32x16_bf16(fr3, *(const bf16x8*)(brow + bslot[2]*8), acc, 0,0,0);
                acc = __builtin_amdgcn_mfma_f32_32x32x16_bf16(fr4, *(const bf16x8*)(brow + bslot[3]*8), acc, 0,0,0);
                bf16x8 frB2 = {};
                if (half == 0) { frB2[0] = w1dv[cb]; frB2[1] = w1av[cb]; }
                acc = __builtin_amdgcn_mfma_f32_32x32x16_bf16(fr2, frB2, acc, 0,0,0);
                __builtin_amdgcn_s_setprio(0);
            }
            float hs = 0.f;
            #pragma unroll
            for (int r = 0; r < 16; ++r) {
                const int e = (r & 3) + 8 * (r >> 2) + 4 * half;
                float h = silu_f(acc[r]);
                if (half == 1 && r == 15) h = 0.f;   // pad row 31
                hs += h;
                sM[wave][e][((g + (e >> 3)) & 3) * 8 + jlow] = bfc(h);
            }
            Hacc[cb] = hs;
            #pragma unroll
            for (int q = 0; q < 2; ++q) {
                const bf16x8 afr  = *(const bf16x8*)&sM[wave][l][((q * 2 + half + (l >> 3)) & 3) * 8];
                const bf16x8 wpfr = *(const bf16x8*)&sW2p[cb * 32 + q * 16 + half * 8];
                accC = __builtin_amdgcn_mfma_f32_32x32x16_bf16(afr, q ? w2e1 : w2e0, accC, 0,0,0);
                accP = __builtin_amdgcn_mfma_f32_32x32x16_bf16(afr, wpfr, accP, 0,0,0);
            }
        }
        // H row into LDS tile (bf16)
        #pragma unroll
        for (int cb = 0; cb < 8; ++cb) {
            const float v = Hacc[cb] + __shfl_xor(Hacc[cb], 32, 64);
            if (lane < 32) sHrows[nloc][cb * 32 + lane] = bfc(v);
        }
        // p: accP cols all equal; lanes l==0 (both halves) scatter 16 rows each
        if (l == 0) {
            #pragma unroll
            for (int q4 = 0; q4 < 4; ++q4) {
                float4 pv = { accP[q4 * 4 + 0], accP[q4 * 4 + 1],
                              accP[q4 * 4 + 2], accP[q4 * 4 + 3] };
                *(float4*)&sP[wave][q4 * 8 + 4 * half] = pv;
            }
        }
        const float pown = sP[wave][l];
        const float pfull = (half == 0 && l < 31) ? (pown + b2p) : 0.f;
        float pd0 = rnx * pfull, pd1 = rny * pfull, pd2 = rnz * pfull;
        #pragma unroll
        for (int m = 1; m <= 32; m <<= 1) {
            pd0 += __shfl_xor(pd0, m, 64);
            pd1 += __shfl_xor(pd1, m, 64);
            pd2 += __shfl_xor(pd2, m, 64);
        }
        if (lane == 0) {
            sPd[nloc][0] = pd0;
            sPd[nloc][1] = pd1;
            sPd[nloc][2] = pd2;
        }
        // e update (bf16 RMW)
        #pragma unroll
        for (int r = 0; r < 16; ++r) {
            const int e = (r & 3) + 8 * (r >> 2) + 4 * half;
            if (e < 31) {
                short* ep = ebuf + ((size_t)((mol * 32 + n) * 31 + e)) * 32 + l;
                *ep = bfc(bf2f(*ep) + accC[r] + b2e);
            }
        }
    }

    __syncthreads();  // H-tile + sPd complete

    // ---- phase 2: s-update via 16x16x32 MFMA (16 rows, no padding)
    {
        const int jb0 = wave * 32;
        const int arow = lane & 15, kg = lane >> 4;   // kg in 0..3
        f32x4 accS0 = {}, accS1 = {};
        #pragma unroll
        for (int k0 = 0; k0 < 256; k0 += 32) {
            const bf16x8 afr = *(const bf16x8*)&sHrows[arow][k0 + kg * 8];
            const bf16x8 bf0 = *(const bf16x8*)&W2sT[(size_t)(jb0 + arow) * 256 + k0 + kg * 8];
            const bf16x8 bf1 = *(const bf16x8*)&W2sT[(size_t)(jb0 + 16 + arow) * 256 + k0 + kg * 8];
            accS0 = __builtin_amdgcn_mfma_f32_16x16x32_bf16(afr, bf0, accS0, 0,0,0);
            accS1 = __builtin_amdgcn_mfma_f32_16x16x32_bf16(afr, bf1, accS1, 0,0,0);
        }
        const int col = lane & 15;
        const int orow = (lane >> 4) * 4;
        const float bv0 = b2[jb0 + col];
        const float bv1 = b2[jb0 + 16 + col];
        #pragma unroll
        for (int r = 0; r < 4; ++r) {
            const int node = node0 + nbase + orow + r;
            {
                float* sp = s + (size_t)node * 256 + jb0 + col;
                const float nv = *sp + accS0[r] * (1.f / 31.f) + bv0;
                *sp = nv;
                sbfOut[(size_t)node * 256 + jb0 + col] = bfc(nv);
            }
            {
                float* sp = s + (size_t)node * 256 + jb0 + 16 + col;
                const float nv = *sp + accS1[r] * (1.f / 31.f) + bv1;
                *sp = nv;
                sbfOut[(size_t)node * 256 + jb0 + 16 + col] = bfc(nv);
            }
        }
    }
    // pos update
    if (t < 48) {
        const int nl = t / 3, c = t % 3;
        const int node = node0 + nbase + nl;
        posOut[(size_t)node * 3 + c] = posIn[(size_t)node * 3 + c] + sPd[nl][c] * (1.f / 31.f);
    }
}

// ---------------------------------------------------------------------------
// MFMA bond kernel: fused U-GEMM prologue, atoms epilogue (silu(s@Wh1)@Wh2),
// and pos output copy. Grid 512, 512 thr. Same XCD swizzle as edge_mfma.
// ---------------------------------------------------------------------------
__global__ __launch_bounds__(512) void bond_mfma(
    const short* __restrict__ sbfA, const short* __restrict__ We1T,
    const float* __restrict__ pos, short* __restrict__ ebuf,
    const short* __restrict__ We1cG, const short* __restrict__ WdP,
    const short* __restrict__ We2img, const short* __restrict__ Wh1T,
    const short* __restrict__ Wh2I,
    const float* __restrict__ be1, const float* __restrict__ be2,
    const float* __restrict__ bh1, const float* __restrict__ bh2,
    float* __restrict__ outA, float* __restrict__ outB,
    float* __restrict__ outPos)
{
    const int blk = blockIdx.x;
    const int mol = (blk & 7) + ((blk >> 4) << 3);
    const int nbase = ((blk >> 3) & 1) * 16;
    const int t = threadIdx.x;
    const int wave = t >> 6, lane = t & 63;
    const int l = lane & 31, half = lane >> 5;
    const int node0 = mol * 32;

    __shared__ __align__(16) short sBg2[128][72];
    __shared__ __align__(16) short sHdnB[8][32][40];
    __shared__ __align__(16) short sU[32][136];
    __shared__ float sPosS[32][4];
    __shared__ __align__(16) short sWd[128];
    short* sSbf = &sHdnB[0][0][0];   // [32][264] view, phase0 only

    {
        const int j = t & 127, g = t >> 7;
        const bf16x8 v = *(const bf16x8*)&We1cG[j * 32 + g * 8];
        const int slot = (g + 3 * ((j >> 3) & 3)) & 7;
        *(bf16x8*)&sBg2[j][slot * 8] = v;
    }
    {
        const int row = t >> 4, ch = (t & 15) * 16;
        const short* src = sbfA + (size_t)(node0 + row) * 256 + ch;
        *(bf16x8*)&sSbf[row * 264 + ch]     = *(const bf16x8*)(src);
        *(bf16x8*)&sSbf[row * 264 + ch + 8] = *(const bf16x8*)(src + 8);
    }
    if (t < 16) *(bf16x8*)&sWd[t * 8] = *(const bf16x8*)&WdP[t * 8];
    if (t < 96) sPosS[t / 3][t % 3] = pos[node0 * 3 + t];
    __syncthreads();

    if (wave < 4) {
        const int j = wave * 32 + l;
        f32x16 accU = {};
        #pragma unroll
        for (int k0 = 0; k0 < 256; k0 += 16) {
            const bf16x8 afr = *(const bf16x8*)&sSbf[l * 264 + k0 + half * 8];
            const bf16x8 bU  = *(const bf16x8*)(We1T + (size_t)j * 256 + k0 + half * 8);
            accU = __builtin_amdgcn_mfma_f32_32x32x16_bf16(afr, bU, accU, 0,0,0);
        }
        const int c3 = (j >> 3) & 3;
        #pragma unroll
        for (int r = 0; r < 16; ++r) {
            const int node = (r & 3) + 8 * (r >> 2) + 4 * half;
            const short uv = bfc(accU[r]);
            const int k = 32 + node;
            const int slot = ((k >> 3) + 3 * c3) & 7;
            sBg2[j][slot * 8 + (k & 7)] = uv;
            sU[node][j] = uv;
        }
    }

    float be1v[4];
    #pragma unroll
    for (int cb = 0; cb < 4; ++cb) be1v[cb] = be1[cb * 32 + l];
    const float be2v = (l < 5) ? be2[l] : 0.f;
    int bslot[4];
    #pragma unroll
    for (int ks = 0; ks < 4; ++ks)
        bslot[ks] = ((ks * 2 + half) + 3 * ((l >> 3) & 3)) & 7;
    __syncthreads();

    bf16x8 efr0[2], efr1[2];
    #pragma unroll
    for (int ni = 0; ni < 2; ++ni) {
        const int n = nbase + wave + ni * 8;
        const short* ebase = ebuf + ((size_t)((mol * 32 + n) * 31 + l)) * 32;
        efr0[ni] = *(const bf16x8*)(ebase + half * 8);
        efr1[ni] = *(const bf16x8*)(ebase + 16 + half * 8);
    }

    #pragma unroll
    for (int ni = 0; ni < 2; ++ni) {
        const int n = nbase + wave + ni * 8;
        const int rrc = (l < 31) ? l : 30;
        const int src = rrc + (rrc >= n ? 1 : 0);
        const float rx = sPosS[n][0] - sPosS[src][0];
        const float ry = sPosS[n][1] - sPosS[src][1];
        const float rz = sPosS[n][2] - sPosS[src][2];
        const float dd = sqrtf(fmaxf(rx * rx + ry * ry + rz * rz, 1e-6f));

        const bf16x8 fr0 = efr0[ni];
        const bf16x8 fr1 = efr1[ni];
        bf16x8 fr2 = {}, fr3, fr4;
        if (half == 0) fr2[0] = bfc(dd);
        #pragma unroll
        for (int jj = 0; jj < 8; ++jj) {
            fr3[jj] = (half * 8 + jj == src)      ? ONEBF : (short)0;
            fr4[jj] = (16 + half * 8 + jj == src) ? ONEBF : (short)0;
        }

        const short* We2i = We2img;
        asm volatile("" : "+s"(We2i));

        f32x16 accC = {};
        const int g = l >> 3, jlow = l & 7;
        #pragma unroll
        for (int cb = 0; cb < 4; ++cb) {
            const bf16x8 w2f0 = *(const bf16x8*)&We2i[(size_t)((cb * 2 + 0) * 64 + lane) * 8];
            const bf16x8 w2f1 = *(const bf16x8*)&We2i[(size_t)((cb * 2 + 1) * 64 + lane) * 8];
            const float uin = bf2f(sU[n][cb * 32 + l]) + be1v[cb];
            f32x16 acc;
            #pragma unroll
            for (int r = 0; r < 16; ++r) acc[r] = uin;
            {
                const short* brow = &sBg2[cb * 32 + l][0];
                acc = __builtin_amdgcn_mfma_f32_32x32x16_bf16(fr0, *(const bf16x8*)(brow + bslot[0]*8), acc, 0,0,0);
                acc = __builtin_amdgcn_mfma_f32_32x32x16_bf16(fr1, *(const bf16x8*)(brow + bslot[1]*8), acc, 0,0,0);
                acc = __builtin_amdgcn_mfma_f32_32x32x16_bf16(fr3, *(const bf16x8*)(brow + bslot[2]*8), acc, 0,0,0);
                acc = __builtin_amdgcn_mfma_f32_32x32x16_bf16(fr4, *(const bf16x8*)(brow + bslot[3]*8), acc, 0,0,0);
                bf16x8 frWd = {};
                if (half == 0) frWd[0] = sWd[cb * 32 + l];
                acc = __builtin_amdgcn_mfma_f32_32x32x16_bf16(fr2, frWd, acc, 0,0,0);
            }
            #pragma unroll
            for (int r = 0; r < 16; ++r) {
                const int e = (r & 3) + 8 * (r >> 2) + 4 * half;
                sHdnB[wave][e][((g + (e >> 3)) & 3) * 8 + jlow] = bfc(silu_f(acc[r]));
            }
            #pragma unroll
            for (int q = 0; q < 2; ++q) {
                const bf16x8 afr = *(const bf16x8*)&sHdnB[wave][l][((q * 2 + half + (l >> 3)) & 3) * 8];
                accC = __builtin_amdgcn_mfma_f32_32x32x16_bf16(afr, q ? w2f1 : w2f0, accC, 0,0,0);
            }
        }
        if (l < 5) {
            #pragma unroll
            for (int r = 0; r < 16; ++r) {
                const int e = (r & 3) + 8 * (r >> 2) + 4 * half;
                if (e < 31) {
                    const int s_ = e + (e >= n ? 1 : 0);
                    const int ge = (mol * 32 + s_) * 31 + (n - (n > s_ ? 1 : 0));
                    outB[(size_t)ge * 5 + l] = accC[r] + be2v;
                }
            }
        }
    }
    if (t < 48) {
        const int nl = t / 3, c = t % 3;
        const int node = node0 + nbase + nl;
        outPos[(size_t)node * 3 + c] = pos[(size_t)node * 3 + c];
    }

    // ---- phase 3: atoms
    __syncthreads();
    {
        short* sA3 = &sU[0][0];
        const int row = t >> 5, ch = (t & 31) * 8;
        *(bf16x8*)&sA3[row * 264 + ch] =
            *(const bf16x8*)(sbfA + (size_t)(node0 + nbase + row) * 256 + ch);
    }
    __syncthreads();
    {
        short* sA3 = &sU[0][0];
        short* sT  = &sBg2[0][0];
        const int jb0 = wave * 32;
        const int arow = lane & 15, kg = lane >> 4;
        f32x4 a0 = {}, a1 = {};
        #pragma unroll
        for (int k0 = 0; k0 < 256; k0 += 32) {
            const bf16x8 afr = *(const bf16x8*)&sA3[arow * 264 + k0 + kg * 8];
            const bf16x8 bw0 = *(const bf16x8*)(Wh1T + (size_t)(jb0 + arow) * 256 + k0 + kg * 8);
            const bf16x8 bw1 = *(const bf16x8*)(Wh1T + (size_t)(jb0 + 16 + arow) * 256 + k0 + kg * 8);
            a0 = __builtin_amdgcn_mfma_f32_16x16x32_bf16(afr, bw0, a0, 0,0,0);
            a1 = __builtin_amdgcn_mfma_f32_16x16x32_bf16(afr, bw1, a1, 0,0,0);
        }
        const int col = lane & 15, orow = (lane >> 4) * 4;
        const float bva = bh1[jb0 + col], bvb = bh1[jb0 + 16 + col];
        #pragma unroll
        for (int r = 0; r < 4; ++r) {
            sT[(orow + r) * 264 + jb0 + col]      = bfc(silu_f(a0[r] + bva));
            sT[(orow + r) * 264 + jb0 + 16 + col] = bfc(silu_f(a1[r] + bvb));
        }
    }
    __syncthreads();
    if (wave == 0) {
        short* sT = &sBg2[0][0];
        const int arow = lane & 15, kg = lane >> 4;
        f32x4 a2 = {};
        #pragma unroll
        for (int k0 = 0; k0 < 256; k0 += 32) {
            const bf16x8 afr = *(const bf16x8*)&sT[arow * 264 + k0 + kg * 8];
            const bf16x8 bfr = *(const bf16x8*)(Wh2I + (size_t)arow * 256 + k0 + kg * 8);
            a2 = __builtin_amdgcn_mfma_f32_16x16x32_bf16(afr, bfr, a2, 0,0,0);
        }
        const int col = lane & 15, orow = (lane >> 4) * 4;
        const float bv = bh2[col];
        #pragma unroll
        for (int r = 0; r < 4; ++r)
            outA[(size_t)(node0 + nbase + orow + r) * 16 + col] = a2[r] + bv;
    }
}

// ---------------------------------------------------------------------------
extern "C" void kernel_launch(void* const* d_in, const int* in_sizes, int n_in,
                              void* d_out, int out_size, void* d_ws, size_t ws_size,
                              hipStream_t stream) {
    const float* x   = (const float*)d_in[0];
    const float* z   = (const float*)d_in[1];
    const float* rot = (const float*)d_in[2];
    const float* ea  = (const float*)d_in[4];
    const float* Wam = (const float*)d_in[6];
    const float* bam = (const float*)d_in[7];
    const float* Wbm = (const float*)d_in[8];
    const float* bbm = (const float*)d_in[9];
    const float* gW1 = (const float*)d_in[10];
    const float* gb1 = (const float*)d_in[11];
    const float* gW2 = (const float*)d_in[12];
    const float* gb2 = (const float*)d_in[13];
    const float* Wh1 = (const float*)d_in[14];
    const float* bh1 = (const float*)d_in[15];
    const float* Wh2 = (const float*)d_in[16];
    const float* bh2 = (const float*)d_in[17];
    const float* We1 = (const float*)d_in[18];
    const float* be1 = (const float*)d_in[19];
    const float* We2 = (const float*)d_in[20];
    const float* be2 = (const float*)d_in[21];
    float* out = (float*)d_out;

    float* ws  = (float*)d_ws;
    float* s    = ws;                       // 8192*256 fp32
    float* pos  = ws + 2097152;             // 8192*3 (ping)
    short* e    = (short*)(ws + 2121728);   // 8192*31*32 bf16
    short* wb   = (short*)(ws + 6184960);   // weight images
    short* sbf0 = (short*)(ws + 6774784);   // 8192*256 bf16 (ping)
    short* sbf1 = (short*)(ws + 10248192);  // 8192*256 bf16 (pong)
    float* pos2 = ws + 16539648;            // 8192*3 (pong)

    init_all<<<840, 256, 0, stream>>>(x, z, rot, Wam, bam, ea, Wbm, bbm,
        gW1, gW2, Wh1, We1, We2, Wh2, s, sbf0, pos, e, wb);

    float* pbuf[2] = { pos, pos2 };
    short* sbb[2] = { sbf0, sbf1 };
    for (int l = 0; l < LAYERS_; ++l) {
        const float* b1 = gb1 + l * 256;
        const float* b2 = gb2 + l * 353;
        edge_mfma<<<2 * N_MOLS, 512, 0, stream>>>(
            sbb[l & 1], wb + OFF_T1 + (size_t)l * 131072,
            pbuf[l & 1], pbuf[(l + 1) & 1], e,
            wb + OFF_W1CG + l * 8192, wb + OFF_W1DA + l * 512,
            wb + OFF_W2P + l * 256, wb + OFF_W2EI + l * 8192,
            wb + OFF_W2ST + (size_t)l * 65536,
            b1, b2, s, sbb[(l + 1) & 1]);
    }
    float* posF = pbuf[LAYERS_ & 1];
    short* sbfF = sbb[LAYERS_ & 1];

    bond_mfma<<<2 * N_MOLS, 512, 0, stream>>>(
        sbfF, wb + OFF_WE1T, posF, e, wb + OFF_WE1CG, wb + OFF_WD,
        wb + OFF_WE2I, wb + OFF_WH1T, wb + OFF_WH2T,
        be1, be2, bh1, bh2, out, out + 131072, out + 131072 + 1269760);
}